// Round 4
// baseline (867.001 us; speedup 1.0000x reference)
//
#include <hip/hip_runtime.h>
#include <hip/hip_bf16.h>

typedef __hip_bfloat16 bf16;

#define BB  8
#define NN  384
#define HH  12
#define HSZ 768
#define DD  64
#define PHH 64

__device__ __forceinline__ float bflo(unsigned u){ union{unsigned q; float f;} c; c.q = u << 16;        return c.f; }
__device__ __forceinline__ float bfhi(unsigned u){ union{unsigned q; float f;} c; c.q = u & 0xffff0000u; return c.f; }
__device__ __forceinline__ float b2f(bf16 x){ return __bfloat162float(x); }
__device__ __forceinline__ bf16  f2b(float f){ return __float2bfloat16(f); }

// ---------------------------------------------------------------------------
// K1: QKV projection.  C(3072x768) = nodes(3072x768) @ W(768x768) + b   (f32)
// 128x128 tile, BK=16, 256 threads, 8x8 per thread.
// Output written in split-head layout (B,H,N,D) f32.  q gets *0.125.
// ---------------------------------------------------------------------------
__global__ __launch_bounds__(256) void k_qkv(
    const float* __restrict__ nodes,
    const float* __restrict__ Wq, const float* __restrict__ bq,
    const float* __restrict__ Wk, const float* __restrict__ bk,
    const float* __restrict__ Wv, const float* __restrict__ bv,
    float* __restrict__ oq, float* __restrict__ okk, float* __restrict__ ov)
{
    const int which = blockIdx.z;
    const float* __restrict__ W   = which==0 ? Wq : (which==1 ? Wk : Wv);
    const float* __restrict__ bia = which==0 ? bq : (which==1 ? bk : bv);
    float* __restrict__ out       = which==0 ? oq : (which==1 ? okk : ov);
    const float scale = which==0 ? 0.125f : 1.0f;

    __shared__ float As[16][132];   // [k][row] transposed
    __shared__ float Bs[16][132];   // [k][col]

    const int row0 = blockIdx.x * 128;
    const int col0 = blockIdx.y * 128;
    const int tid = threadIdx.x;
    const int tx = tid & 15, ty = tid >> 4;

    float acc[8][8];
    #pragma unroll
    for (int i=0;i<8;i++){
        #pragma unroll
        for (int j=0;j<8;j++) acc[i][j]=0.f;
    }

    for (int k0 = 0; k0 < HSZ; k0 += 16) {
        {
            const int r = tid >> 1, kk = (tid & 1) * 8;
            const float4* ap = reinterpret_cast<const float4*>(nodes + (size_t)(row0 + r) * HSZ + k0 + kk);
            float4 a0 = ap[0], a1 = ap[1];
            As[kk+0][r]=a0.x; As[kk+1][r]=a0.y; As[kk+2][r]=a0.z; As[kk+3][r]=a0.w;
            As[kk+4][r]=a1.x; As[kk+5][r]=a1.y; As[kk+6][r]=a1.z; As[kk+7][r]=a1.w;

            const int kb = tid >> 4, c0 = (tid & 15) * 8;
            const float4* bp = reinterpret_cast<const float4*>(W + (size_t)(k0 + kb) * HSZ + col0 + c0);
            float4 b0 = bp[0], b1 = bp[1];
            Bs[kb][c0+0]=b0.x; Bs[kb][c0+1]=b0.y; Bs[kb][c0+2]=b0.z; Bs[kb][c0+3]=b0.w;
            Bs[kb][c0+4]=b1.x; Bs[kb][c0+5]=b1.y; Bs[kb][c0+6]=b1.z; Bs[kb][c0+7]=b1.w;
        }
        __syncthreads();
        #pragma unroll
        for (int kk = 0; kk < 16; kk++) {
            float a[8], b[8];
            *reinterpret_cast<float4*>(&a[0]) = *reinterpret_cast<const float4*>(&As[kk][ty*8]);
            *reinterpret_cast<float4*>(&a[4]) = *reinterpret_cast<const float4*>(&As[kk][ty*8+4]);
            *reinterpret_cast<float4*>(&b[0]) = *reinterpret_cast<const float4*>(&Bs[kk][tx*8]);
            *reinterpret_cast<float4*>(&b[4]) = *reinterpret_cast<const float4*>(&Bs[kk][tx*8+4]);
            #pragma unroll
            for (int i=0;i<8;i++)
                #pragma unroll
                for (int j=0;j<8;j++) acc[i][j] = fmaf(a[i], b[j], acc[i][j]);
        }
        __syncthreads();
    }
    #pragma unroll
    for (int j=0;j<8;j++){
        const int c = col0 + tx*8 + j;
        const int h = c >> 6, d = c & 63;
        const float bv_ = bia[c];
        #pragma unroll
        for (int i=0;i<8;i++){
            const int rr = row0 + ty*8 + i;
            const int b_ = rr / NN, n_ = rr % NN;
            out[(((size_t)b_*HH + h)*NN + n_)*DD + d] = (acc[i][j] + bv_) * scale;
        }
    }
}

// ---------------------------------------------------------------------------
// K1b: qsk[b,h,i,ph] = sum_d Wsk[ph,d]*q_s[b,h,i,d]; qbsk = q_s . bsk
// one wave per row (b*H+h)*N+i ; 4 rows per 256-thread block
// ---------------------------------------------------------------------------
__global__ __launch_bounds__(256) void k_qsk(
    const float* __restrict__ q_s, const float* __restrict__ Wsk,
    const float* __restrict__ bsk, float* __restrict__ qsk, float* __restrict__ qbsk)
{
    const int lane = threadIdx.x & 63;
    const int row = blockIdx.x * 4 + (threadIdx.x >> 6);
    const float qd = q_s[(size_t)row * DD + lane];
    float t = qd * bsk[lane];
    #pragma unroll
    for (int o = 32; o > 0; o >>= 1) t += __shfl_down(t, o, 64);
    if (lane == 0) qbsk[row] = t;
    float acc = 0.f;
    const float* wr = Wsk + lane * DD;
    #pragma unroll 8
    for (int d = 0; d < DD; d++) acc = fmaf(wr[d], __shfl(qd, d, 64), acc);
    qsk[(size_t)row * DD + lane] = acc;
}

// ---------------------------------------------------------------------------
// K2: content scores wc[b,h,i,j] = q_s[b,h,i,:] . k[b,h,j,:]   (f32)
// per (b,h): 384x384, K=64.  64x64 tile, 4x4/thread.
// ---------------------------------------------------------------------------
__global__ __launch_bounds__(256) void k_scores(
    const float* __restrict__ q_s, const float* __restrict__ kk_, float* __restrict__ wc)
{
    const int bh = blockIdx.z;
    const float* __restrict__ Q = q_s + (size_t)bh * NN * DD;
    const float* __restrict__ K = kk_ + (size_t)bh * NN * DD;
    __shared__ float Qs[64][68];   // [d][i]
    __shared__ float Ks[64][68];   // [d][j]
    const int tid = threadIdx.x;
    const int i0 = blockIdx.x * 64, j0 = blockIdx.y * 64;
    {
        const int r = tid >> 2, d0 = (tid & 3) * 16;
        const float4* qp = reinterpret_cast<const float4*>(Q + (size_t)(i0 + r) * DD + d0);
        const float4* kp = reinterpret_cast<const float4*>(K + (size_t)(j0 + r) * DD + d0);
        #pragma unroll
        for (int e = 0; e < 4; e++) {
            float4 x = qp[e];
            Qs[d0+4*e+0][r]=x.x; Qs[d0+4*e+1][r]=x.y; Qs[d0+4*e+2][r]=x.z; Qs[d0+4*e+3][r]=x.w;
            float4 y = kp[e];
            Ks[d0+4*e+0][r]=y.x; Ks[d0+4*e+1][r]=y.y; Ks[d0+4*e+2][r]=y.z; Ks[d0+4*e+3][r]=y.w;
        }
    }
    __syncthreads();
    const int tx = tid & 15, ty = tid >> 4;
    float acc[4][4] = {};
    #pragma unroll 4
    for (int d = 0; d < 64; d++) {
        float a[4], b[4];
        *reinterpret_cast<float4*>(a) = *reinterpret_cast<const float4*>(&Qs[d][ty*4]);
        *reinterpret_cast<float4*>(b) = *reinterpret_cast<const float4*>(&Ks[d][tx*4]);
        #pragma unroll
        for (int i=0;i<4;i++)
            #pragma unroll
            for (int j=0;j<4;j++) acc[i][j] = fmaf(a[i], b[j], acc[i][j]);
    }
    #pragma unroll
    for (int i=0;i<4;i++){
        const size_t ro = ((size_t)bh*NN + i0 + ty*4 + i)*NN + j0 + tx*4;
        float4 o; o.x=acc[i][0]; o.y=acc[i][1]; o.z=acc[i][2]; o.w=acc[i][3];
        *reinterpret_cast<float4*>(&wc[ro]) = o;
    }
}

// ---------------------------------------------------------------------------
// K3: fused per-(b,i):  LN(paths[b,i,:,:]) in LDS (bf16); for each head:
//   s_j = wc + qbsk + bias + pLN[j,:].qsk ; softmax; write w (f32);
//   pagg[h,:] = sum_j w_j * pLN[j,:]
// 384 threads (1 thread = 1 j / 1 path row)
// ---------------------------------------------------------------------------
__global__ __launch_bounds__(384) void k_soft(
    const float* __restrict__ paths, const float* __restrict__ bias,
    const float* __restrict__ pg, const float* __restrict__ pb,
    const float* __restrict__ wc, const float* __restrict__ qsk,
    const float* __restrict__ qbsk,
    float* __restrict__ pagg, float* __restrict__ w_out)
{
    const int bi = blockIdx.x;
    const int b = bi / NN, i = bi % NN;
    __shared__ bf16  pLN[384][68];   // row stride 136 B
    __shared__ float sbuf[384];
    __shared__ float qs[64];
    __shared__ float part[6][64];
    __shared__ float red[8];
    __shared__ float scalars[2];
    __shared__ float pgf[64], pbf[64];
    const int tid = threadIdx.x;
    const int wid = tid >> 6, lane = tid & 63;

    if (tid < 64) { pgf[tid] = pg[tid]; pbf[tid] = pb[tid]; }
    __syncthreads();

    {   // LayerNorm of path row `tid`
        const float4* src = reinterpret_cast<const float4*>(paths + ((size_t)bi * NN + tid) * PHH);
        float x[64];
        #pragma unroll
        for (int t = 0; t < 16; t++) {
            float4 u = src[t];
            x[4*t]=u.x; x[4*t+1]=u.y; x[4*t+2]=u.z; x[4*t+3]=u.w;
        }
        float m = 0.f;
        #pragma unroll
        for (int t = 0; t < 64; t++) m += x[t];
        m *= (1.f/64.f);
        float vs = 0.f;
        #pragma unroll
        for (int t = 0; t < 64; t++) { float d_ = x[t]-m; vs = fmaf(d_,d_,vs); }
        const float rs = rsqrtf(vs*(1.f/64.f) + 1e-5f);
        #pragma unroll
        for (int ph = 0; ph < 64; ph++)
            pLN[tid][ph] = f2b((x[ph]-m)*rs*pgf[ph] + pbf[ph]);
    }
    const float biasv = bias[b*NN + tid];
    __syncthreads();

    for (int h = 0; h < HH; h++) {
        const size_t bhi = ((size_t)(b*HH + h)*NN + i);
        if (tid < 64) qs[tid] = qsk[bhi*DD + tid];
        if (tid == 64) scalars[0] = qbsk[bhi];
        __syncthreads();
        float s = wc[bhi*NN + tid] + scalars[0] + biasv;
        {
            const unsigned* prow = reinterpret_cast<const unsigned*>(&pLN[tid][0]);
            #pragma unroll
            for (int t = 0; t < 32; t++) {
                const unsigned u = prow[t];
                s = fmaf(bflo(u), qs[2*t],   s);
                s = fmaf(bfhi(u), qs[2*t+1], s);
            }
        }
        float m = s;
        #pragma unroll
        for (int o = 32; o > 0; o >>= 1) m = fmaxf(m, __shfl_xor(m, o, 64));
        if (lane == 0) red[wid] = m;
        __syncthreads();
        if (tid == 0) {
            float mm = red[0];
            for (int w2 = 1; w2 < 6; w2++) mm = fmaxf(mm, red[w2]);
            scalars[1] = mm;
        }
        __syncthreads();
        const float e = __expf(s - scalars[1]);
        float sum = e;
        #pragma unroll
        for (int o = 32; o > 0; o >>= 1) sum += __shfl_xor(sum, o, 64);
        if (lane == 0) red[wid] = sum;
        __syncthreads();
        if (tid == 0) {
            float ss = 0.f;
            for (int w2 = 0; w2 < 6; w2++) ss += red[w2];
            scalars[0] = 1.f / ss;
        }
        __syncthreads();
        const float wgt = e * scalars[0];
        w_out[bhi*NN + tid] = wgt;
        sbuf[tid] = wgt;
        __syncthreads();
        {   // pagg partial: wave `wid` covers j = wid*64..+63, lane = ph
            float acc = 0.f;
            const int jb = wid * 64;
            #pragma unroll 8
            for (int t = 0; t < 64; t++)
                acc = fmaf(sbuf[jb + t], b2f(pLN[jb + t][lane]), acc);
            part[wid][lane] = acc;
        }
        __syncthreads();
        if (tid < 64) {
            float a2 = part[0][tid];
            #pragma unroll
            for (int w2 = 1; w2 < 6; w2++) a2 += part[w2][tid];
            pagg[bhi*DD + tid] = a2;
        }
        __syncthreads();
    }
}

// ---------------------------------------------------------------------------
// K4: attn[b,i,h*64+d] = sum_j w[b,h,i,j]*v[b,h,j,d] + pagg[b,h,i,:]@Wsv + bsv
// per (b,h), 64-row tiles over i, full D=64.
// ---------------------------------------------------------------------------
__global__ __launch_bounds__(256) void k_av(
    const float* __restrict__ w, const float* __restrict__ v_,
    const float* __restrict__ pagg, const float* __restrict__ Wsv,
    const float* __restrict__ bsv, float* __restrict__ attn)
{
    const int bh = blockIdx.y;
    const int b = bh / HH, h = bh % HH;
    const int i0 = blockIdx.x * 64;
    __shared__ float Ws_[64][68];   // [i][j]  (later [i][ph])
    __shared__ float Vs[64][68];    // [j][d]  (later [ph][d])
    const int tid = threadIdx.x;
    const int tx = tid & 15, ty = tid >> 4;
    float acc[4][4] = {};
    for (int j0 = 0; j0 < NN; j0 += 64) {
        {
            const int r = tid >> 2, c0 = (tid & 3) * 16;
            const float4* wp = reinterpret_cast<const float4*>(w + ((size_t)bh*NN + i0 + r)*NN + j0 + c0);
            #pragma unroll
            for (int e = 0; e < 4; e++) {
                float4 t = wp[e];
                Ws_[r][c0+4*e+0]=t.x; Ws_[r][c0+4*e+1]=t.y; Ws_[r][c0+4*e+2]=t.z; Ws_[r][c0+4*e+3]=t.w;
            }
            const float4* vp = reinterpret_cast<const float4*>(v_ + ((size_t)bh*NN + j0 + r)*DD + c0);
            #pragma unroll
            for (int e = 0; e < 4; e++) {
                float4 t = vp[e];
                Vs[r][c0+4*e+0]=t.x; Vs[r][c0+4*e+1]=t.y; Vs[r][c0+4*e+2]=t.z; Vs[r][c0+4*e+3]=t.w;
            }
        }
        __syncthreads();
        #pragma unroll 4
        for (int jj = 0; jj < 64; jj++) {
            float a[4], bb[4];
            #pragma unroll
            for (int e = 0; e < 4; e++) a[e] = Ws_[ty*4+e][jj];
            *reinterpret_cast<float4*>(bb) = *reinterpret_cast<const float4*>(&Vs[jj][tx*4]);
            #pragma unroll
            for (int i2=0;i2<4;i2++)
                #pragma unroll
                for (int j2=0;j2<4;j2++) acc[i2][j2] = fmaf(a[i2], bb[j2], acc[i2][j2]);
        }
        __syncthreads();
    }
    {   // structural part
        const int r = tid >> 2, c0 = (tid & 3) * 16;
        const float4* pp = reinterpret_cast<const float4*>(pagg + ((size_t)bh*NN + i0 + r)*PHH + c0);
        #pragma unroll
        for (int e = 0; e < 4; e++) {
            float4 t = pp[e];
            Ws_[r][c0+4*e+0]=t.x; Ws_[r][c0+4*e+1]=t.y; Ws_[r][c0+4*e+2]=t.z; Ws_[r][c0+4*e+3]=t.w;
        }
        const float4* sp = reinterpret_cast<const float4*>(Wsv + (size_t)r*DD + c0);
        #pragma unroll
        for (int e = 0; e < 4; e++) {
            float4 t = sp[e];
            Vs[r][c0+4*e+0]=t.x; Vs[r][c0+4*e+1]=t.y; Vs[r][c0+4*e+2]=t.z; Vs[r][c0+4*e+3]=t.w;
        }
    }
    __syncthreads();
    #pragma unroll 4
    for (int ph = 0; ph < 64; ph++) {
        float a[4], bb[4];
        #pragma unroll
        for (int e = 0; e < 4; e++) a[e] = Ws_[ty*4+e][ph];
        *reinterpret_cast<float4*>(bb) = *reinterpret_cast<const float4*>(&Vs[ph][tx*4]);
        #pragma unroll
        for (int i2=0;i2<4;i2++)
            #pragma unroll
            for (int j2=0;j2<4;j2++) acc[i2][j2] = fmaf(a[i2], bb[j2], acc[i2][j2]);
    }
    #pragma unroll
    for (int ii=0;ii<4;ii++){
        const int irow = i0 + ty*4 + ii;
        float4 o;
        o.x = acc[ii][0] + bsv[tx*4+0];
        o.y = acc[ii][1] + bsv[tx*4+1];
        o.z = acc[ii][2] + bsv[tx*4+2];
        o.w = acc[ii][3] + bsv[tx*4+3];
        *reinterpret_cast<float4*>(&attn[((size_t)b*NN + irow)*HSZ + h*DD + tx*4]) = o;
    }
}

// ---------------------------------------------------------------------------
// K5a: tres = nodes + relu(attn @ Wo + bo)      (128x128 tile like K1)
// ---------------------------------------------------------------------------
__global__ __launch_bounds__(256) void k_proj(
    const float* __restrict__ attn, const float* __restrict__ Wo,
    const float* __restrict__ bo, const float* __restrict__ nodes,
    float* __restrict__ tres)
{
    __shared__ float As[16][132];
    __shared__ float Bs[16][132];
    const int row0 = blockIdx.x * 128, col0 = blockIdx.y * 128;
    const int tid = threadIdx.x, tx = tid & 15, ty = tid >> 4;
    float acc[8][8];
    #pragma unroll
    for (int i=0;i<8;i++){
        #pragma unroll
        for (int j=0;j<8;j++) acc[i][j]=0.f;
    }
    for (int k0 = 0; k0 < HSZ; k0 += 16) {
        {
            const int r = tid >> 1, kk = (tid & 1) * 8;
            const float4* ap = reinterpret_cast<const float4*>(attn + (size_t)(row0 + r)*HSZ + k0 + kk);
            float4 a0 = ap[0], a1 = ap[1];
            As[kk+0][r]=a0.x; As[kk+1][r]=a0.y; As[kk+2][r]=a0.z; As[kk+3][r]=a0.w;
            As[kk+4][r]=a1.x; As[kk+5][r]=a1.y; As[kk+6][r]=a1.z; As[kk+7][r]=a1.w;
            const int kb = tid >> 4, c0 = (tid & 15) * 8;
            const float4* bp = reinterpret_cast<const float4*>(Wo + (size_t)(k0+kb)*HSZ + col0 + c0);
            float4 b0 = bp[0], b1 = bp[1];
            Bs[kb][c0+0]=b0.x; Bs[kb][c0+1]=b0.y; Bs[kb][c0+2]=b0.z; Bs[kb][c0+3]=b0.w;
            Bs[kb][c0+4]=b1.x; Bs[kb][c0+5]=b1.y; Bs[kb][c0+6]=b1.z; Bs[kb][c0+7]=b1.w;
        }
        __syncthreads();
        #pragma unroll
        for (int kk = 0; kk < 16; kk++) {
            float a[8], b[8];
            *reinterpret_cast<float4*>(&a[0]) = *reinterpret_cast<const float4*>(&As[kk][ty*8]);
            *reinterpret_cast<float4*>(&a[4]) = *reinterpret_cast<const float4*>(&As[kk][ty*8+4]);
            *reinterpret_cast<float4*>(&b[0]) = *reinterpret_cast<const float4*>(&Bs[kk][tx*8]);
            *reinterpret_cast<float4*>(&b[4]) = *reinterpret_cast<const float4*>(&Bs[kk][tx*8+4]);
            #pragma unroll
            for (int i=0;i<8;i++)
                #pragma unroll
                for (int j=0;j<8;j++) acc[i][j] = fmaf(a[i], b[j], acc[i][j]);
        }
        __syncthreads();
    }
    #pragma unroll
    for (int j=0;j<8;j++){
        const int c = col0 + tx*8 + j;
        const float bov = bo[c];
        #pragma unroll
        for (int i=0;i<8;i++){
            const int rr = row0 + ty*8 + i;
            float val = fmaxf(acc[i][j] + bov, 0.f);
            val += nodes[(size_t)rr*HSZ + c];
            tres[(size_t)rr*HSZ + c] = val;
        }
    }
}

// ---------------------------------------------------------------------------
// K5b: row LayerNorm over 768 -> out0 (f32).  1 block per row.
// ---------------------------------------------------------------------------
__global__ __launch_bounds__(256) void k_ln(
    const float* __restrict__ tres, const float* __restrict__ g,
    const float* __restrict__ bta, float* __restrict__ out0)
{
    const int row = blockIdx.x;
    const float* x = tres + (size_t)row * HSZ;
    const int tid = threadIdx.x;
    const int wid = tid >> 6, lane = tid & 63;
    __shared__ float r4[4];
    __shared__ float sc[2];
    float v0 = x[tid], v1 = x[tid+256], v2 = x[tid+512];
    float s = v0 + v1 + v2;
    #pragma unroll
    for (int o = 32; o > 0; o >>= 1) s += __shfl_xor(s, o, 64);
    if (lane == 0) r4[wid] = s;
    __syncthreads();
    if (tid == 0) sc[0] = (r4[0]+r4[1]+r4[2]+r4[3]) * (1.f/768.f);
    __syncthreads();
    const float m = sc[0];
    const float d0 = v0-m, d1 = v1-m, d2 = v2-m;
    float vs = d0*d0 + d1*d1 + d2*d2;
    #pragma unroll
    for (int o = 32; o > 0; o >>= 1) vs += __shfl_xor(vs, o, 64);
    if (lane == 0) r4[wid] = vs;
    __syncthreads();
    if (tid == 0) sc[1] = rsqrtf((r4[0]+r4[1]+r4[2]+r4[3]) * (1.f/768.f) + 1e-5f);
    __syncthreads();
    const float rs = sc[1];
    out0[(size_t)row*HSZ + tid      ] = d0*rs*g[tid      ] + bta[tid      ];
    out0[(size_t)row*HSZ + tid + 256] = d1*rs*g[tid + 256] + bta[tid + 256];
    out0[(size_t)row*HSZ + tid + 512] = d2*rs*g[tid + 512] + bta[tid + 512];
}

// ---------------------------------------------------------------------------
extern "C" void kernel_launch(void* const* d_in, const int* in_sizes, int n_in,
                              void* d_out, int out_size, void* d_ws, size_t ws_size,
                              hipStream_t stream)
{
    (void)in_sizes; (void)n_in; (void)out_size; (void)ws_size;
    const float* nodes = (const float*)d_in[0];
    const float* bias  = (const float*)d_in[1];
    const float* paths = (const float*)d_in[2];
    const float* Wq = (const float*)d_in[3];
    const float* bq = (const float*)d_in[4];
    const float* Wk = (const float*)d_in[5];
    const float* bk = (const float*)d_in[6];
    const float* Wv = (const float*)d_in[7];
    const float* bv = (const float*)d_in[8];
    const float* Wsk= (const float*)d_in[9];
    const float* bsk= (const float*)d_in[10];
    const float* Wsv= (const float*)d_in[11];
    const float* bsv= (const float*)d_in[12];
    const float* Wo = (const float*)d_in[13];
    const float* bo = (const float*)d_in[14];
    const float* lng= (const float*)d_in[15];
    const float* lnb= (const float*)d_in[16];
    const float* plg= (const float*)d_in[17];
    const float* plb= (const float*)d_in[18];

    // workspace layout (floats), lifetime-based reuse:
    float* ws   = (float*)d_ws;
    float* q_s  = ws;
    float* kbuf = ws + 2359296;
    float* vbuf = ws + 4718592;
    float* qsk  = ws + 7077888;
    float* qbsk = ws + 9437184;
    float* wc   = ws + 9474048;
    float* attn = q_s;
    float* pagg = kbuf;
    float* tres = wc;

    float* out0 = (float*)d_out;
    float* wout = out0 + (size_t)BB*NN*HSZ;

    hipLaunchKernelGGL(k_qkv,    dim3(24,6,3), dim3(256), 0, stream,
                       nodes, Wq,bq, Wk,bk, Wv,bv, q_s, kbuf, vbuf);
    hipLaunchKernelGGL(k_qsk,    dim3(9216),   dim3(256), 0, stream,
                       q_s, Wsk, bsk, qsk, qbsk);
    hipLaunchKernelGGL(k_scores, dim3(6,6,96), dim3(256), 0, stream,
                       q_s, kbuf, wc);
    hipLaunchKernelGGL(k_soft,   dim3(3072),   dim3(384), 0, stream,
                       paths, bias, plg, plb, wc, qsk, qbsk, pagg, wout);
    hipLaunchKernelGGL(k_av,     dim3(6,96),   dim3(256), 0, stream,
                       wout, vbuf, pagg, Wsv, bsv, attn);
    hipLaunchKernelGGL(k_proj,   dim3(24,6),   dim3(256), 0, stream,
                       attn, Wo, bo, nodes, tres);
    hipLaunchKernelGGL(k_ln,     dim3(3072),   dim3(256), 0, stream,
                       tres, lng, lnb, out0);
}

// Round 5
// 656.084 us; speedup vs baseline: 1.3215x; 1.3215x over previous
//
#include <hip/hip_runtime.h>
#include <hip/hip_bf16.h>

typedef __hip_bfloat16 bf16;

#define BB  8
#define NN  384
#define HH  12
#define HSZ 768
#define DD  64
#define PHH 64
#define PSTR 385   // pLNT32 row stride in u32 words (odd -> conflict-free columns)

__device__ __forceinline__ float bflo(unsigned u){ union{unsigned q; float f;} c; c.q = u << 16;        return c.f; }
__device__ __forceinline__ float bfhi(unsigned u){ union{unsigned q; float f;} c; c.q = u & 0xffff0000u; return c.f; }
__device__ __forceinline__ float b2f(bf16 x){ return __bfloat162float(x); }
__device__ __forceinline__ bf16  f2b(float f){ return __float2bfloat16(f); }

// pack two f32 into a u32 of two RNE-rounded bf16 (lo, hi)
__device__ __forceinline__ unsigned pk2bf(float lo, float hi){
    union{float f; unsigned u;} a, b; a.f = lo; b.f = hi;
    unsigned ua = a.u + 0x7fffu + ((a.u >> 16) & 1u);
    unsigned ub = b.u + 0x7fffu + ((b.u >> 16) & 1u);
    return (ua >> 16) | (ub & 0xffff0000u);
}

// ---------------------------------------------------------------------------
// K1: QKV projection.  C(3072x768) = nodes(3072x768) @ W(768x768) + b   (f32)
// 128x128 tile, BK=16, 256 threads, 8x8 per thread.
// Output written in split-head layout (B,H,N,D) f32.  q gets *0.125.
// ---------------------------------------------------------------------------
__global__ __launch_bounds__(256) void k_qkv(
    const float* __restrict__ nodes,
    const float* __restrict__ Wq, const float* __restrict__ bq,
    const float* __restrict__ Wk, const float* __restrict__ bk,
    const float* __restrict__ Wv, const float* __restrict__ bv,
    float* __restrict__ oq, float* __restrict__ okk, float* __restrict__ ov)
{
    const int which = blockIdx.z;
    const float* __restrict__ W   = which==0 ? Wq : (which==1 ? Wk : Wv);
    const float* __restrict__ bia = which==0 ? bq : (which==1 ? bk : bv);
    float* __restrict__ out       = which==0 ? oq : (which==1 ? okk : ov);
    const float scale = which==0 ? 0.125f : 1.0f;

    __shared__ float As[16][132];   // [k][row] transposed
    __shared__ float Bs[16][132];   // [k][col]

    const int row0 = blockIdx.x * 128;
    const int col0 = blockIdx.y * 128;
    const int tid = threadIdx.x;
    const int tx = tid & 15, ty = tid >> 4;

    float acc[8][8];
    #pragma unroll
    for (int i=0;i<8;i++){
        #pragma unroll
        for (int j=0;j<8;j++) acc[i][j]=0.f;
    }

    for (int k0 = 0; k0 < HSZ; k0 += 16) {
        {
            const int r = tid >> 1, kk = (tid & 1) * 8;
            const float4* ap = reinterpret_cast<const float4*>(nodes + (size_t)(row0 + r) * HSZ + k0 + kk);
            float4 a0 = ap[0], a1 = ap[1];
            As[kk+0][r]=a0.x; As[kk+1][r]=a0.y; As[kk+2][r]=a0.z; As[kk+3][r]=a0.w;
            As[kk+4][r]=a1.x; As[kk+5][r]=a1.y; As[kk+6][r]=a1.z; As[kk+7][r]=a1.w;

            const int kb = tid >> 4, c0 = (tid & 15) * 8;
            const float4* bp = reinterpret_cast<const float4*>(W + (size_t)(k0 + kb) * HSZ + col0 + c0);
            float4 b0 = bp[0], b1 = bp[1];
            Bs[kb][c0+0]=b0.x; Bs[kb][c0+1]=b0.y; Bs[kb][c0+2]=b0.z; Bs[kb][c0+3]=b0.w;
            Bs[kb][c0+4]=b1.x; Bs[kb][c0+5]=b1.y; Bs[kb][c0+6]=b1.z; Bs[kb][c0+7]=b1.w;
        }
        __syncthreads();
        #pragma unroll
        for (int kk = 0; kk < 16; kk++) {
            float a[8], b[8];
            *reinterpret_cast<float4*>(&a[0]) = *reinterpret_cast<const float4*>(&As[kk][ty*8]);
            *reinterpret_cast<float4*>(&a[4]) = *reinterpret_cast<const float4*>(&As[kk][ty*8+4]);
            *reinterpret_cast<float4*>(&b[0]) = *reinterpret_cast<const float4*>(&Bs[kk][tx*8]);
            *reinterpret_cast<float4*>(&b[4]) = *reinterpret_cast<const float4*>(&Bs[kk][tx*8+4]);
            #pragma unroll
            for (int i=0;i<8;i++)
                #pragma unroll
                for (int j=0;j<8;j++) acc[i][j] = fmaf(a[i], b[j], acc[i][j]);
        }
        __syncthreads();
    }
    #pragma unroll
    for (int j=0;j<8;j++){
        const int c = col0 + tx*8 + j;
        const int h = c >> 6, d = c & 63;
        const float bv_ = bia[c];
        #pragma unroll
        for (int i=0;i<8;i++){
            const int rr = row0 + ty*8 + i;
            const int b_ = rr / NN, n_ = rr % NN;
            out[(((size_t)b_*HH + h)*NN + n_)*DD + d] = (acc[i][j] + bv_) * scale;
        }
    }
}

// ---------------------------------------------------------------------------
// K1b: qsk[b,h,i,ph] = sum_d Wsk[ph,d]*q_s[b,h,i,d]; qbsk = q_s . bsk
// one wave per row (b*H+h)*N+i ; 4 rows per 256-thread block
// ---------------------------------------------------------------------------
__global__ __launch_bounds__(256) void k_qsk(
    const float* __restrict__ q_s, const float* __restrict__ Wsk,
    const float* __restrict__ bsk, float* __restrict__ qsk, float* __restrict__ qbsk)
{
    const int lane = threadIdx.x & 63;
    const int row = blockIdx.x * 4 + (threadIdx.x >> 6);
    const float qd = q_s[(size_t)row * DD + lane];
    float t = qd * bsk[lane];
    #pragma unroll
    for (int o = 32; o > 0; o >>= 1) t += __shfl_down(t, o, 64);
    if (lane == 0) qbsk[row] = t;
    float acc = 0.f;
    const float* wr = Wsk + lane * DD;
    #pragma unroll 8
    for (int d = 0; d < DD; d++) acc = fmaf(wr[d], __shfl(qd, d, 64), acc);
    qsk[(size_t)row * DD + lane] = acc;
}

// ---------------------------------------------------------------------------
// K2: content scores wc[b,h,i,j] = q_s[b,h,i,:] . k[b,h,j,:]   (f32)
// per (b,h): 384x384, K=64.  64x64 tile, 4x4/thread.
// ---------------------------------------------------------------------------
__global__ __launch_bounds__(256) void k_scores(
    const float* __restrict__ q_s, const float* __restrict__ kk_, float* __restrict__ wc)
{
    const int bh = blockIdx.z;
    const float* __restrict__ Q = q_s + (size_t)bh * NN * DD;
    const float* __restrict__ K = kk_ + (size_t)bh * NN * DD;
    __shared__ float Qs[64][68];   // [d][i]
    __shared__ float Ks[64][68];   // [d][j]
    const int tid = threadIdx.x;
    const int i0 = blockIdx.x * 64, j0 = blockIdx.y * 64;
    {
        const int r = tid >> 2, d0 = (tid & 3) * 16;
        const float4* qp = reinterpret_cast<const float4*>(Q + (size_t)(i0 + r) * DD + d0);
        const float4* kp = reinterpret_cast<const float4*>(K + (size_t)(j0 + r) * DD + d0);
        #pragma unroll
        for (int e = 0; e < 4; e++) {
            float4 x = qp[e];
            Qs[d0+4*e+0][r]=x.x; Qs[d0+4*e+1][r]=x.y; Qs[d0+4*e+2][r]=x.z; Qs[d0+4*e+3][r]=x.w;
            float4 y = kp[e];
            Ks[d0+4*e+0][r]=y.x; Ks[d0+4*e+1][r]=y.y; Ks[d0+4*e+2][r]=y.z; Ks[d0+4*e+3][r]=y.w;
        }
    }
    __syncthreads();
    const int tx = tid & 15, ty = tid >> 4;
    float acc[4][4] = {};
    #pragma unroll 4
    for (int d = 0; d < 64; d++) {
        float a[4], b[4];
        *reinterpret_cast<float4*>(a) = *reinterpret_cast<const float4*>(&Qs[d][ty*4]);
        *reinterpret_cast<float4*>(b) = *reinterpret_cast<const float4*>(&Ks[d][tx*4]);
        #pragma unroll
        for (int i=0;i<4;i++)
            #pragma unroll
            for (int j=0;j<4;j++) acc[i][j] = fmaf(a[i], b[j], acc[i][j]);
    }
    #pragma unroll
    for (int i=0;i<4;i++){
        const size_t ro = ((size_t)bh*NN + i0 + ty*4 + i)*NN + j0 + tx*4;
        float4 o; o.x=acc[i][0]; o.y=acc[i][1]; o.z=acc[i][2]; o.w=acc[i][3];
        *reinterpret_cast<float4*>(&wc[ro]) = o;
    }
}

// ---------------------------------------------------------------------------
// K3: fused per-(b,i).  Wave-local head processing:
//   phase 1 (all 384 threads): LN(paths[b,i,j,:]) -> pLNT32 (transposed,
//     packed bf16 pairs).  ONE barrier.
//   phase 2: wave w handles heads {w, w+6}; lane owns 6 score columns.
//     scores via shfl-broadcast qsk registers; wave-local softmax (no
//     barriers, no serial sections); pagg via packed-bf16 half-split dot.
// ---------------------------------------------------------------------------
__global__ __launch_bounds__(384) void k_soft(
    const float* __restrict__ paths, const float* __restrict__ bias,
    const float* __restrict__ pg, const float* __restrict__ pb,
    const float* __restrict__ wc, const float* __restrict__ qsk,
    const float* __restrict__ qbsk,
    float* __restrict__ pagg, float* __restrict__ w_out)
{
    const int bi = blockIdx.x;
    const int b = bi / NN, i = bi % NN;
    __shared__ unsigned pLNT[32 * PSTR];   // [w][j] bf16 pair (2w, 2w+1); 49280 B
    __shared__ float sbuf[6][NN];          // per-wave softmax weights; 9216 B
    __shared__ float pgf[64], pbf[64];
    const int tid  = threadIdx.x;
    const int wv   = tid >> 6, lane = tid & 63;

    if (tid < 64) { pgf[tid] = pg[tid]; pbf[tid] = pb[tid]; }
    __syncthreads();

    {   // LayerNorm of path row j = tid, store transposed+packed
        const float4* src = reinterpret_cast<const float4*>(paths + ((size_t)bi * NN + tid) * PHH);
        float x[64];
        #pragma unroll
        for (int t = 0; t < 16; t++) {
            float4 u = src[t];
            x[4*t]=u.x; x[4*t+1]=u.y; x[4*t+2]=u.z; x[4*t+3]=u.w;
        }
        float m0 = 0.f, m1 = 0.f;
        #pragma unroll
        for (int t = 0; t < 32; t++){ m0 += x[2*t]; m1 += x[2*t+1]; }
        const float m = (m0+m1)*(1.f/64.f);
        float v0 = 0.f, v1 = 0.f;
        #pragma unroll
        for (int t = 0; t < 32; t++){
            float a = x[2*t]-m, c = x[2*t+1]-m;
            v0 = fmaf(a,a,v0); v1 = fmaf(c,c,v1);
        }
        const float rs = rsqrtf((v0+v1)*(1.f/64.f) + 1e-5f);
        #pragma unroll
        for (int w = 0; w < 32; w++){
            const float lo = (x[2*w  ]-m)*rs*pgf[2*w  ] + pbf[2*w  ];
            const float hi = (x[2*w+1]-m)*rs*pgf[2*w+1] + pbf[2*w+1];
            pLNT[w*PSTR + tid] = pk2bf(lo, hi);
        }
    }
    __syncthreads();

    float bias_c[6];
    #pragma unroll
    for (int c = 0; c < 6; c++) bias_c[c] = bias[b*NN + c*64 + lane];

    for (int hh = 0; hh < 2; hh++) {
        const int h = wv + hh*6;
        const size_t bhi = ((size_t)(b*HH + h)*NN + i);
        const float qd = qsk[bhi*DD + lane];
        const float qb = qbsk[bhi];
        float s[6];
        #pragma unroll
        for (int c = 0; c < 6; c++) s[c] = wc[bhi*NN + c*64 + lane] + qb + bias_c[c];
        // structural scores: s[c] += sum_d qs[d] * pLN[j_c][d]
        #pragma unroll 8
        for (int w = 0; w < 32; w++) {
            const float qlo = __shfl(qd, 2*w,   64);
            const float qhi = __shfl(qd, 2*w+1, 64);
            #pragma unroll
            for (int c = 0; c < 6; c++) {
                const unsigned u = pLNT[w*PSTR + c*64 + lane];
                s[c] = fmaf(bflo(u), qlo, s[c]);
                s[c] = fmaf(bfhi(u), qhi, s[c]);
            }
        }
        // wave-local softmax over 384 values
        float m = s[0];
        #pragma unroll
        for (int c = 1; c < 6; c++) m = fmaxf(m, s[c]);
        #pragma unroll
        for (int o = 32; o > 0; o >>= 1) m = fmaxf(m, __shfl_xor(m, o, 64));
        float e[6], sum = 0.f;
        #pragma unroll
        for (int c = 0; c < 6; c++){ e[c] = __expf(s[c]-m); sum += e[c]; }
        #pragma unroll
        for (int o = 32; o > 0; o >>= 1) sum += __shfl_xor(sum, o, 64);
        const float inv = 1.f / sum;
        #pragma unroll
        for (int c = 0; c < 6; c++){
            const float wgt = e[c]*inv;
            w_out[bhi*NN + c*64 + lane] = wgt;
            sbuf[wv][c*64 + lane] = wgt;
        }
        // same-wave LDS write->read fence (cross-lane through sbuf[wv])
        asm volatile("s_waitcnt lgkmcnt(0)" ::: "memory");
        // pagg: lane owns bf16-pair column wL, j-half hf
        const int wL = lane & 31, hf = lane >> 5;
        float a0 = 0.f, a1 = 0.f;
        const unsigned* prow = &pLNT[wL*PSTR + hf*192];
        const float*    wrow = &sbuf[wv][hf*192];
        #pragma unroll 8
        for (int j = 0; j < 192; j++) {
            const unsigned u = prow[j];
            const float   wj = wrow[j];
            a0 = fmaf(bflo(u), wj, a0);
            a1 = fmaf(bfhi(u), wj, a1);
        }
        a0 += __shfl_xor(a0, 32, 64);
        a1 += __shfl_xor(a1, 32, 64);
        if (hf == 0) {
            float2 o2; o2.x = a0; o2.y = a1;
            *reinterpret_cast<float2*>(&pagg[bhi*DD + 2*wL]) = o2;
        }
    }
}

// ---------------------------------------------------------------------------
// K4: attn[b,i,h*64+d] = sum_j w[b,h,i,j]*v[b,h,j,d] + pagg[b,h,i,:]@Wsv + bsv
// per (b,h), 64-row tiles over i, full D=64.
// ---------------------------------------------------------------------------
__global__ __launch_bounds__(256) void k_av(
    const float* __restrict__ w, const float* __restrict__ v_,
    const float* __restrict__ pagg, const float* __restrict__ Wsv,
    const float* __restrict__ bsv, float* __restrict__ attn)
{
    const int bh = blockIdx.y;
    const int b = bh / HH, h = bh % HH;
    const int i0 = blockIdx.x * 64;
    __shared__ float Ws_[64][68];   // [i][j]  (later [i][ph])
    __shared__ float Vs[64][68];    // [j][d]  (later [ph][d])
    const int tid = threadIdx.x;
    const int tx = tid & 15, ty = tid >> 4;
    float acc[4][4] = {};
    for (int j0 = 0; j0 < NN; j0 += 64) {
        {
            const int r = tid >> 2, c0 = (tid & 3) * 16;
            const float4* wp = reinterpret_cast<const float4*>(w + ((size_t)bh*NN + i0 + r)*NN + j0 + c0);
            #pragma unroll
            for (int e = 0; e < 4; e++) {
                float4 t = wp[e];
                Ws_[r][c0+4*e+0]=t.x; Ws_[r][c0+4*e+1]=t.y; Ws_[r][c0+4*e+2]=t.z; Ws_[r][c0+4*e+3]=t.w;
            }
            const float4* vp = reinterpret_cast<const float4*>(v_ + ((size_t)bh*NN + j0 + r)*DD + c0);
            #pragma unroll
            for (int e = 0; e < 4; e++) {
                float4 t = vp[e];
                Vs[r][c0+4*e+0]=t.x; Vs[r][c0+4*e+1]=t.y; Vs[r][c0+4*e+2]=t.z; Vs[r][c0+4*e+3]=t.w;
            }
        }
        __syncthreads();
        #pragma unroll 4
        for (int jj = 0; jj < 64; jj++) {
            float a[4], bb[4];
            #pragma unroll
            for (int e = 0; e < 4; e++) a[e] = Ws_[ty*4+e][jj];
            *reinterpret_cast<float4*>(bb) = *reinterpret_cast<const float4*>(&Vs[jj][tx*4]);
            #pragma unroll
            for (int i2=0;i2<4;i2++)
                #pragma unroll
                for (int j2=0;j2<4;j2++) acc[i2][j2] = fmaf(a[i2], bb[j2], acc[i2][j2]);
        }
        __syncthreads();
    }
    {   // structural part
        const int r = tid >> 2, c0 = (tid & 3) * 16;
        const float4* pp = reinterpret_cast<const float4*>(pagg + ((size_t)bh*NN + i0 + r)*PHH + c0);
        #pragma unroll
        for (int e = 0; e < 4; e++) {
            float4 t = pp[e];
            Ws_[r][c0+4*e+0]=t.x; Ws_[r][c0+4*e+1]=t.y; Ws_[r][c0+4*e+2]=t.z; Ws_[r][c0+4*e+3]=t.w;
        }
        const float4* sp = reinterpret_cast<const float4*>(Wsv + (size_t)r*DD + c0);
        #pragma unroll
        for (int e = 0; e < 4; e++) {
            float4 t = sp[e];
            Vs[r][c0+4*e+0]=t.x; Vs[r][c0+4*e+1]=t.y; Vs[r][c0+4*e+2]=t.z; Vs[r][c0+4*e+3]=t.w;
        }
    }
    __syncthreads();
    #pragma unroll 4
    for (int ph = 0; ph < 64; ph++) {
        float a[4], bb[4];
        #pragma unroll
        for (int e = 0; e < 4; e++) a[e] = Ws_[ty*4+e][ph];
        *reinterpret_cast<float4*>(bb) = *reinterpret_cast<const float4*>(&Vs[ph][tx*4]);
        #pragma unroll
        for (int i2=0;i2<4;i2++)
            #pragma unroll
            for (int j2=0;j2<4;j2++) acc[i2][j2] = fmaf(a[i2], bb[j2], acc[i2][j2]);
    }
    #pragma unroll
    for (int ii=0;ii<4;ii++){
        const int irow = i0 + ty*4 + ii;
        float4 o;
        o.x = acc[ii][0] + bsv[tx*4+0];
        o.y = acc[ii][1] + bsv[tx*4+1];
        o.z = acc[ii][2] + bsv[tx*4+2];
        o.w = acc[ii][3] + bsv[tx*4+3];
        *reinterpret_cast<float4*>(&attn[((size_t)b*NN + irow)*HSZ + h*DD + tx*4]) = o;
    }
}

// ---------------------------------------------------------------------------
// K5a: tres = nodes + relu(attn @ Wo + bo)      (128x128 tile like K1)
// ---------------------------------------------------------------------------
__global__ __launch_bounds__(256) void k_proj(
    const float* __restrict__ attn, const float* __restrict__ Wo,
    const float* __restrict__ bo, const float* __restrict__ nodes,
    float* __restrict__ tres)
{
    __shared__ float As[16][132];
    __shared__ float Bs[16][132];
    const int row0 = blockIdx.x * 128, col0 = blockIdx.y * 128;
    const int tid = threadIdx.x, tx = tid & 15, ty = tid >> 4;
    float acc[8][8];
    #pragma unroll
    for (int i=0;i<8;i++){
        #pragma unroll
        for (int j=0;j<8;j++) acc[i][j]=0.f;
    }
    for (int k0 = 0; k0 < HSZ; k0 += 16) {
        {
            const int r = tid >> 1, kk = (tid & 1) * 8;
            const float4* ap = reinterpret_cast<const float4*>(attn + (size_t)(row0 + r)*HSZ + k0 + kk);
            float4 a0 = ap[0], a1 = ap[1];
            As[kk+0][r]=a0.x; As[kk+1][r]=a0.y; As[kk+2][r]=a0.z; As[kk+3][r]=a0.w;
            As[kk+4][r]=a1.x; As[kk+5][r]=a1.y; As[kk+6][r]=a1.z; As[kk+7][r]=a1.w;
            const int kb = tid >> 4, c0 = (tid & 15) * 8;
            const float4* bp = reinterpret_cast<const float4*>(Wo + (size_t)(k0+kb)*HSZ + col0 + c0);
            float4 b0 = bp[0], b1 = bp[1];
            Bs[kb][c0+0]=b0.x; Bs[kb][c0+1]=b0.y; Bs[kb][c0+2]=b0.z; Bs[kb][c0+3]=b0.w;
            Bs[kb][c0+4]=b1.x; Bs[kb][c0+5]=b1.y; Bs[kb][c0+6]=b1.z; Bs[kb][c0+7]=b1.w;
        }
        __syncthreads();
        #pragma unroll
        for (int kk = 0; kk < 16; kk++) {
            float a[8], b[8];
            *reinterpret_cast<float4*>(&a[0]) = *reinterpret_cast<const float4*>(&As[kk][ty*8]);
            *reinterpret_cast<float4*>(&a[4]) = *reinterpret_cast<const float4*>(&As[kk][ty*8+4]);
            *reinterpret_cast<float4*>(&b[0]) = *reinterpret_cast<const float4*>(&Bs[kk][tx*8]);
            *reinterpret_cast<float4*>(&b[4]) = *reinterpret_cast<const float4*>(&Bs[kk][tx*8+4]);
            #pragma unroll
            for (int i=0;i<8;i++)
                #pragma unroll
                for (int j=0;j<8;j++) acc[i][j] = fmaf(a[i], b[j], acc[i][j]);
        }
        __syncthreads();
    }
    #pragma unroll
    for (int j=0;j<8;j++){
        const int c = col0 + tx*8 + j;
        const float bov = bo[c];
        #pragma unroll
        for (int i=0;i<8;i++){
            const int rr = row0 + ty*8 + i;
            float val = fmaxf(acc[i][j] + bov, 0.f);
            val += nodes[(size_t)rr*HSZ + c];
            tres[(size_t)rr*HSZ + c] = val;
        }
    }
}

// ---------------------------------------------------------------------------
// K5b: row LayerNorm over 768 -> out0 (f32).  1 block per row.
// ---------------------------------------------------------------------------
__global__ __launch_bounds__(256) void k_ln(
    const float* __restrict__ tres, const float* __restrict__ g,
    const float* __restrict__ bta, float* __restrict__ out0)
{
    const int row = blockIdx.x;
    const float* x = tres + (size_t)row * HSZ;
    const int tid = threadIdx.x;
    const int wid = tid >> 6, lane = tid & 63;
    __shared__ float r4[4];
    __shared__ float sc[2];
    float v0 = x[tid], v1 = x[tid+256], v2 = x[tid+512];
    float s = v0 + v1 + v2;
    #pragma unroll
    for (int o = 32; o > 0; o >>= 1) s += __shfl_xor(s, o, 64);
    if (lane == 0) r4[wid] = s;
    __syncthreads();
    if (tid == 0) sc[0] = (r4[0]+r4[1]+r4[2]+r4[3]) * (1.f/768.f);
    __syncthreads();
    const float m = sc[0];
    const float d0 = v0-m, d1 = v1-m, d2 = v2-m;
    float vs = d0*d0 + d1*d1 + d2*d2;
    #pragma unroll
    for (int o = 32; o > 0; o >>= 1) vs += __shfl_xor(vs, o, 64);
    if (lane == 0) r4[wid] = vs;
    __syncthreads();
    if (tid == 0) sc[1] = rsqrtf((r4[0]+r4[1]+r4[2]+r4[3]) * (1.f/768.f) + 1e-5f);
    __syncthreads();
    const float rs = sc[1];
    out0[(size_t)row*HSZ + tid      ] = d0*rs*g[tid      ] + bta[tid      ];
    out0[(size_t)row*HSZ + tid + 256] = d1*rs*g[tid + 256] + bta[tid + 256];
    out0[(size_t)row*HSZ + tid + 512] = d2*rs*g[tid + 512] + bta[tid + 512];
}

// ---------------------------------------------------------------------------
extern "C" void kernel_launch(void* const* d_in, const int* in_sizes, int n_in,
                              void* d_out, int out_size, void* d_ws, size_t ws_size,
                              hipStream_t stream)
{
    (void)in_sizes; (void)n_in; (void)out_size; (void)ws_size;
    const float* nodes = (const float*)d_in[0];
    const float* bias  = (const float*)d_in[1];
    const float* paths = (const float*)d_in[2];
    const float* Wq = (const float*)d_in[3];
    const float* bq = (const float*)d_in[4];
    const float* Wk = (const float*)d_in[5];
    const float* bk = (const float*)d_in[6];
    const float* Wv = (const float*)d_in[7];
    const float* bv = (const float*)d_in[8];
    const float* Wsk= (const float*)d_in[9];
    const float* bsk= (const float*)d_in[10];
    const float* Wsv= (const float*)d_in[11];
    const float* bsv= (const float*)d_in[12];
    const float* Wo = (const float*)d_in[13];
    const float* bo = (const float*)d_in[14];
    const float* lng= (const float*)d_in[15];
    const float* lnb= (const float*)d_in[16];
    const float* plg= (const float*)d_in[17];
    const float* plb= (const float*)d_in[18];

    // workspace layout (floats), lifetime-based reuse:
    float* ws   = (float*)d_ws;
    float* q_s  = ws;
    float* kbuf = ws + 2359296;
    float* vbuf = ws + 4718592;
    float* qsk  = ws + 7077888;
    float* qbsk = ws + 9437184;
    float* wc   = ws + 9474048;
    float* attn = q_s;
    float* pagg = kbuf;
    float* tres = wc;

    float* out0 = (float*)d_out;
    float* wout = out0 + (size_t)BB*NN*HSZ;

    hipLaunchKernelGGL(k_qkv,    dim3(24,6,3), dim3(256), 0, stream,
                       nodes, Wq,bq, Wk,bk, Wv,bv, q_s, kbuf, vbuf);
    hipLaunchKernelGGL(k_qsk,    dim3(9216),   dim3(256), 0, stream,
                       q_s, Wsk, bsk, qsk, qbsk);
    hipLaunchKernelGGL(k_scores, dim3(6,6,96), dim3(256), 0, stream,
                       q_s, kbuf, wc);
    hipLaunchKernelGGL(k_soft,   dim3(3072),   dim3(384), 0, stream,
                       paths, bias, plg, plb, wc, qsk, qbsk, pagg, wout);
    hipLaunchKernelGGL(k_av,     dim3(6,96),   dim3(256), 0, stream,
                       wout, vbuf, pagg, Wsv, bsv, attn);
    hipLaunchKernelGGL(k_proj,   dim3(24,6),   dim3(256), 0, stream,
                       attn, Wo, bo, nodes, tres);
    hipLaunchKernelGGL(k_ln,     dim3(3072),   dim3(256), 0, stream,
                       tres, lng, lnb, out0);
}

// Round 6
// 547.576 us; speedup vs baseline: 1.5833x; 1.1982x over previous
//
#include <hip/hip_runtime.h>
#include <hip/hip_bf16.h>

typedef __hip_bfloat16 bf16;
typedef __attribute__((ext_vector_type(8))) short short8b;   // 8 bf16 (MFMA operand)
typedef __attribute__((ext_vector_type(4))) float f32x4;     // MFMA accumulator

#define BB  8
#define NN  384
#define HH  12
#define HSZ 768
#define DD  64
#define PHH 64
#define PSTR 384   // pLNT row stride in u32 words

__device__ __forceinline__ float bflo(unsigned u){ union{unsigned q; float f;} c; c.q = u << 16;        return c.f; }
__device__ __forceinline__ float bfhi(unsigned u){ union{unsigned q; float f;} c; c.q = u & 0xffff0000u; return c.f; }

// pack two f32 into a u32 of two RNE-rounded bf16 (lo, hi)
__device__ __forceinline__ unsigned pk2bf(float lo, float hi){
    union{float f; unsigned u;} a, b; a.f = lo; b.f = hi;
    unsigned ua = a.u + 0x7fffu + ((a.u >> 16) & 1u);
    unsigned ub = b.u + 0x7fffu + ((b.u >> 16) & 1u);
    return (ua >> 16) | (ub & 0xffff0000u);
}

union U8 { uint4 u; short8b v; };

// ---------------------------------------------------------------------------
// K1: QKV projection, MFMA bf16.  C(3072x768) = nodes @ W + b  (f32 in/out)
// 128x128 tile, BK=32, 256 thr = 4 waves (2x2 quadrants), 4x4 16x16 frags.
// A: [m][k] bf16, 80B row stride.  B: W read column-wise (coalesced per
// instr), stored [n][k] bf16, 80B stride.  Output split-head (B,H,N,D) f32,
// q scaled by 0.125.
// ---------------------------------------------------------------------------
__global__ __launch_bounds__(256) void k_qkv(
    const float* __restrict__ nodes,
    const float* __restrict__ Wq, const float* __restrict__ bq,
    const float* __restrict__ Wk, const float* __restrict__ bk,
    const float* __restrict__ Wv, const float* __restrict__ bv,
    float* __restrict__ oq, float* __restrict__ okk, float* __restrict__ ov)
{
    const int which = blockIdx.z;
    const float* __restrict__ W   = which==0 ? Wq : (which==1 ? Wk : Wv);
    const float* __restrict__ bia = which==0 ? bq : (which==1 ? bk : bv);
    float* __restrict__ out       = which==0 ? oq : (which==1 ? okk : ov);
    const float scale = which==0 ? 0.125f : 1.0f;

    __shared__ __align__(16) unsigned Alds[128*20];  // [m][k-pair], stride 20 words (80B)
    __shared__ __align__(16) unsigned Blds[128*20];  // [n][k-pair]

    const int row0 = blockIdx.x * 128;
    const int col0 = blockIdx.y * 128;
    const int tid  = threadIdx.x;
    const int wv   = tid >> 6, lane = tid & 63;
    const int wm   = wv & 1,  wn   = wv >> 1;     // wave quadrant (2x2 of 64x64)
    const int fr   = lane & 15, kg = lane >> 4;   // frag row/col, k-group

    f32x4 acc[4][4];
    #pragma unroll
    for (int i=0;i<4;i++){
        #pragma unroll
        for (int j=0;j<4;j++){ acc[i][j][0]=0.f; acc[i][j][1]=0.f; acc[i][j][2]=0.f; acc[i][j][3]=0.f; }
    }

    for (int k0 = 0; k0 < HSZ; k0 += 32) {
        {   // stage A: thread -> row m=tid>>1, k-half kh=tid&1 (16 f32)
            const int m = tid >> 1, kh = tid & 1;
            const float4* ap = reinterpret_cast<const float4*>(nodes + (size_t)(row0 + m)*HSZ + k0 + kh*16);
            float4 a0 = ap[0], a1 = ap[1], a2 = ap[2], a3 = ap[3];
            uint4 p0, p1;
            p0.x = pk2bf(a0.x,a0.y); p0.y = pk2bf(a0.z,a0.w);
            p0.z = pk2bf(a1.x,a1.y); p0.w = pk2bf(a1.z,a1.w);
            p1.x = pk2bf(a2.x,a2.y); p1.y = pk2bf(a2.z,a2.w);
            p1.z = pk2bf(a3.x,a3.y); p1.w = pk2bf(a3.z,a3.w);
            *reinterpret_cast<uint4*>(&Alds[m*20 + kh*8    ]) = p0;
            *reinterpret_cast<uint4*>(&Alds[m*20 + kh*8 + 4]) = p1;
        }
        {   // stage B: thread -> col n=tid&127, k-quarter kq=tid>>7 (16 k's, strided reads)
            const int n = tid & 127, kq = tid >> 7;
            const float* wp = W + (size_t)(k0 + kq*16)*HSZ + col0 + n;
            float x[16];
            #pragma unroll
            for (int j = 0; j < 16; j++) x[j] = wp[(size_t)j*HSZ];
            uint4 p0, p1;
            p0.x = pk2bf(x[0],x[1]);   p0.y = pk2bf(x[2],x[3]);
            p0.z = pk2bf(x[4],x[5]);   p0.w = pk2bf(x[6],x[7]);
            p1.x = pk2bf(x[8],x[9]);   p1.y = pk2bf(x[10],x[11]);
            p1.z = pk2bf(x[12],x[13]); p1.w = pk2bf(x[14],x[15]);
            *reinterpret_cast<uint4*>(&Blds[n*20 + kq*8    ]) = p0;
            *reinterpret_cast<uint4*>(&Blds[n*20 + kq*8 + 4]) = p1;
        }
        __syncthreads();
        U8 au[4], bu[4];
        #pragma unroll
        for (int t = 0; t < 4; t++) {
            au[t].u = *reinterpret_cast<const uint4*>(&Alds[(wm*64 + t*16 + fr)*20 + kg*4]);
            bu[t].u = *reinterpret_cast<const uint4*>(&Blds[(wn*64 + t*16 + fr)*20 + kg*4]);
        }
        #pragma unroll
        for (int mt = 0; mt < 4; mt++)
            #pragma unroll
            for (int nt = 0; nt < 4; nt++)
                acc[mt][nt] = __builtin_amdgcn_mfma_f32_16x16x32_bf16(
                    au[mt].v, bu[nt].v, acc[mt][nt], 0, 0, 0);
        __syncthreads();
    }
    // epilogue: C/D layout col=lane&15, row=(lane>>4)*4+reg  [verified m89]
    #pragma unroll
    for (int nt = 0; nt < 4; nt++) {
        const int col = col0 + wn*64 + nt*16 + fr;
        const int h = col >> 6, d = col & 63;
        const float bv_ = bia[col];
        #pragma unroll
        for (int mt = 0; mt < 4; mt++) {
            #pragma unroll
            for (int r = 0; r < 4; r++) {
                const int m = row0 + wm*64 + mt*16 + kg*4 + r;
                const int b_ = m / NN, n_ = m % NN;
                out[(((size_t)b_*HH + h)*NN + n_)*DD + d] = (acc[mt][nt][r] + bv_) * scale;
            }
        }
    }
}

// ---------------------------------------------------------------------------
// K1b: qsk[b,h,i,ph] = sum_d Wsk[ph,d]*q_s[b,h,i,d]; qbsk = q_s . bsk
// ---------------------------------------------------------------------------
__global__ __launch_bounds__(256) void k_qsk(
    const float* __restrict__ q_s, const float* __restrict__ Wsk,
    const float* __restrict__ bsk, float* __restrict__ qsk, float* __restrict__ qbsk)
{
    const int lane = threadIdx.x & 63;
    const int row = blockIdx.x * 4 + (threadIdx.x >> 6);
    const float qd = q_s[(size_t)row * DD + lane];
    float t = qd * bsk[lane];
    #pragma unroll
    for (int o = 32; o > 0; o >>= 1) t += __shfl_down(t, o, 64);
    if (lane == 0) qbsk[row] = t;
    float acc = 0.f;
    const float* wr = Wsk + lane * DD;
    #pragma unroll 8
    for (int d = 0; d < DD; d++) acc = fmaf(wr[d], __shfl(qd, d, 64), acc);
    qsk[(size_t)row * DD + lane] = acc;
}

// ---------------------------------------------------------------------------
// K2: content scores wc[b,h,i,j] = q . k   (f32), 64x64 tile, 4x4/thread
// ---------------------------------------------------------------------------
__global__ __launch_bounds__(256) void k_scores(
    const float* __restrict__ q_s, const float* __restrict__ kk_, float* __restrict__ wc)
{
    const int bh = blockIdx.z;
    const float* __restrict__ Q = q_s + (size_t)bh * NN * DD;
    const float* __restrict__ K = kk_ + (size_t)bh * NN * DD;
    __shared__ float Qs[64][68];
    __shared__ float Ks[64][68];
    const int tid = threadIdx.x;
    const int i0 = blockIdx.x * 64, j0 = blockIdx.y * 64;
    {
        const int r = tid >> 2, d0 = (tid & 3) * 16;
        const float4* qp = reinterpret_cast<const float4*>(Q + (size_t)(i0 + r) * DD + d0);
        const float4* kp = reinterpret_cast<const float4*>(K + (size_t)(j0 + r) * DD + d0);
        #pragma unroll
        for (int e = 0; e < 4; e++) {
            float4 x = qp[e];
            Qs[d0+4*e+0][r]=x.x; Qs[d0+4*e+1][r]=x.y; Qs[d0+4*e+2][r]=x.z; Qs[d0+4*e+3][r]=x.w;
            float4 y = kp[e];
            Ks[d0+4*e+0][r]=y.x; Ks[d0+4*e+1][r]=y.y; Ks[d0+4*e+2][r]=y.z; Ks[d0+4*e+3][r]=y.w;
        }
    }
    __syncthreads();
    const int tx = tid & 15, ty = tid >> 4;
    float acc[4][4] = {};
    #pragma unroll 4
    for (int d = 0; d < 64; d++) {
        float a[4], b[4];
        *reinterpret_cast<float4*>(a) = *reinterpret_cast<const float4*>(&Qs[d][ty*4]);
        *reinterpret_cast<float4*>(b) = *reinterpret_cast<const float4*>(&Ks[d][tx*4]);
        #pragma unroll
        for (int i=0;i<4;i++)
            #pragma unroll
            for (int j=0;j<4;j++) acc[i][j] = fmaf(a[i], b[j], acc[i][j]);
    }
    #pragma unroll
    for (int i=0;i<4;i++){
        const size_t ro = ((size_t)bh*NN + i0 + ty*4 + i)*NN + j0 + tx*4;
        float4 o; o.x=acc[i][0]; o.y=acc[i][1]; o.z=acc[i][2]; o.w=acc[i][3];
        *reinterpret_cast<float4*>(&wc[ro]) = o;
    }
}

// ---------------------------------------------------------------------------
// K3: fused per-(b,i).  LDS = 54,272 B -> 3 blocks/CU.
//   pLNT: [ph-pair][j] packed bf16, stride 384 words.
//   sw:   [wave][j-pair] packed bf16 softmax weights.
//   pagg reads use per-lane rotation (bank spread at stride-384).
// ---------------------------------------------------------------------------
__global__ __launch_bounds__(384) void k_soft(
    const float* __restrict__ paths, const float* __restrict__ bias,
    const float* __restrict__ pg, const float* __restrict__ pb,
    const float* __restrict__ wc, const float* __restrict__ qsk,
    const float* __restrict__ qbsk,
    float* __restrict__ pagg, float* __restrict__ w_out)
{
    const int bi = blockIdx.x;
    const int b = bi / NN, i = bi % NN;
    __shared__ __align__(16) unsigned pLNT[32 * PSTR];  // 49152 B
    __shared__ unsigned sw[6][192];                     // 4608 B
    __shared__ float pgf[64], pbf[64];                  // 512 B
    const int tid  = threadIdx.x;
    const int wv   = tid >> 6, lane = tid & 63;

    if (tid < 64) { pgf[tid] = pg[tid]; pbf[tid] = pb[tid]; }
    __syncthreads();

    {   // LayerNorm of path row j = tid, store transposed+packed
        const float4* src = reinterpret_cast<const float4*>(paths + ((size_t)bi * NN + tid) * PHH);
        float x[64];
        #pragma unroll
        for (int t = 0; t < 16; t++) {
            float4 u = src[t];
            x[4*t]=u.x; x[4*t+1]=u.y; x[4*t+2]=u.z; x[4*t+3]=u.w;
        }
        float m0 = 0.f, m1 = 0.f;
        #pragma unroll
        for (int t = 0; t < 32; t++){ m0 += x[2*t]; m1 += x[2*t+1]; }
        const float m = (m0+m1)*(1.f/64.f);
        float v0 = 0.f, v1 = 0.f;
        #pragma unroll
        for (int t = 0; t < 32; t++){
            float a = x[2*t]-m, c = x[2*t+1]-m;
            v0 = fmaf(a,a,v0); v1 = fmaf(c,c,v1);
        }
        const float rs = rsqrtf((v0+v1)*(1.f/64.f) + 1e-5f);
        #pragma unroll
        for (int w = 0; w < 32; w++){
            const float lo = (x[2*w  ]-m)*rs*pgf[2*w  ] + pbf[2*w  ];
            const float hi = (x[2*w+1]-m)*rs*pgf[2*w+1] + pbf[2*w+1];
            pLNT[w*PSTR + tid] = pk2bf(lo, hi);
        }
    }
    __syncthreads();

    float bias_c[6];
    #pragma unroll
    for (int c = 0; c < 6; c++) bias_c[c] = bias[b*NN + c*64 + lane];

    const int wL = lane & 31, hf = lane >> 5;

    for (int hh = 0; hh < 2; hh++) {
        const int h = wv + hh*6;
        const size_t bhi = ((size_t)(b*HH + h)*NN + i);
        const float qd = qsk[bhi*DD + lane];
        const float qb = qbsk[bhi];
        float s[6];
        #pragma unroll
        for (int c = 0; c < 6; c++) s[c] = wc[bhi*NN + c*64 + lane] + qb + bias_c[c];
        // structural scores
        #pragma unroll 8
        for (int w = 0; w < 32; w++) {
            const float qlo = __shfl(qd, 2*w,   64);
            const float qhi = __shfl(qd, 2*w+1, 64);
            #pragma unroll
            for (int c = 0; c < 6; c++) {
                const unsigned u = pLNT[w*PSTR + c*64 + lane];
                s[c] = fmaf(bflo(u), qlo, s[c]);
                s[c] = fmaf(bfhi(u), qhi, s[c]);
            }
        }
        // wave-local softmax over 384 values
        float m = s[0];
        #pragma unroll
        for (int c = 1; c < 6; c++) m = fmaxf(m, s[c]);
        #pragma unroll
        for (int o = 32; o > 0; o >>= 1) m = fmaxf(m, __shfl_xor(m, o, 64));
        float e[6], sum = 0.f;
        #pragma unroll
        for (int c = 0; c < 6; c++){ e[c] = __expf(s[c]-m); sum += e[c]; }
        #pragma unroll
        for (int o = 32; o > 0; o >>= 1) sum += __shfl_xor(sum, o, 64);
        const float inv = 1.f / sum;
        // write w_out (global) + packed weights to sw
        #pragma unroll
        for (int c = 0; c < 6; c++){
            const float wgt = e[c]*inv;
            w_out[bhi*NN + c*64 + lane] = wgt;
            const float oth = __shfl_xor(wgt, 1, 64);
            const unsigned pk = (lane & 1) ? pk2bf(oth, wgt) : pk2bf(wgt, oth);
            const int t = c*32 + (lane >> 1);
            // balanced write split: even lanes c<3, odd lanes c>=3
            if (((lane & 1) == 0) == (c < 3)) sw[wv][t] = pk;
        }
        asm volatile("s_waitcnt lgkmcnt(0)" ::: "memory");   // same-wave LDS fence
        // pagg: lane owns ph-pair wL, j-half hf; rotated pair index for banks
        float a0 = 0.f, a1 = 0.f;
        const unsigned long long* prow64 =
            reinterpret_cast<const unsigned long long*>(&pLNT[wL*PSTR]);
        const unsigned* swrow = &sw[wv][0];
        #pragma unroll 4
        for (int t = 0; t < 96; t++) {
            int idx = t + wL; if (idx >= 96) idx -= 96;
            const int p = hf*96 + idx;
            const unsigned long long pp = prow64[p];
            const unsigned p0 = (unsigned)pp, p1 = (unsigned)(pp >> 32);
            const unsigned w2 = swrow[p];
            const float wlo = bflo(w2), whi = bfhi(w2);
            a0 = fmaf(bflo(p1), whi, fmaf(bflo(p0), wlo, a0));
            a1 = fmaf(bfhi(p1), whi, fmaf(bfhi(p0), wlo, a1));
        }
        a0 += __shfl_xor(a0, 32, 64);
        a1 += __shfl_xor(a1, 32, 64);
        if (hf == 0) {
            float2 o2; o2.x = a0; o2.y = a1;
            *reinterpret_cast<float2*>(&pagg[bhi*DD + 2*wL]) = o2;
        }
    }
}

// ---------------------------------------------------------------------------
// K4: attn = w@v + pagg@Wsv + bsv   per (b,h), 64-row tiles
// ---------------------------------------------------------------------------
__global__ __launch_bounds__(256) void k_av(
    const float* __restrict__ w, const float* __restrict__ v_,
    const float* __restrict__ pagg, const float* __restrict__ Wsv,
    const float* __restrict__ bsv, float* __restrict__ attn)
{
    const int bh = blockIdx.y;
    const int b = bh / HH, h = bh % HH;
    const int i0 = blockIdx.x * 64;
    __shared__ float Ws_[64][68];
    __shared__ float Vs[64][68];
    const int tid = threadIdx.x;
    const int tx = tid & 15, ty = tid >> 4;
    float acc[4][4] = {};
    for (int j0 = 0; j0 < NN; j0 += 64) {
        {
            const int r = tid >> 2, c0 = (tid & 3) * 16;
            const float4* wp = reinterpret_cast<const float4*>(w + ((size_t)bh*NN + i0 + r)*NN + j0 + c0);
            #pragma unroll
            for (int e = 0; e < 4; e++) {
                float4 t = wp[e];
                Ws_[r][c0+4*e+0]=t.x; Ws_[r][c0+4*e+1]=t.y; Ws_[r][c0+4*e+2]=t.z; Ws_[r][c0+4*e+3]=t.w;
            }
            const float4* vp = reinterpret_cast<const float4*>(v_ + ((size_t)bh*NN + j0 + r)*DD + c0);
            #pragma unroll
            for (int e = 0; e < 4; e++) {
                float4 t = vp[e];
                Vs[r][c0+4*e+0]=t.x; Vs[r][c0+4*e+1]=t.y; Vs[r][c0+4*e+2]=t.z; Vs[r][c0+4*e+3]=t.w;
            }
        }
        __syncthreads();
        #pragma unroll 4
        for (int jj = 0; jj < 64; jj++) {
            float a[4], bb[4];
            #pragma unroll
            for (int e = 0; e < 4; e++) a[e] = Ws_[ty*4+e][jj];
            *reinterpret_cast<float4*>(bb) = *reinterpret_cast<const float4*>(&Vs[jj][tx*4]);
            #pragma unroll
            for (int i2=0;i2<4;i2++)
                #pragma unroll
                for (int j2=0;j2<4;j2++) acc[i2][j2] = fmaf(a[i2], bb[j2], acc[i2][j2]);
        }
        __syncthreads();
    }
    {
        const int r = tid >> 2, c0 = (tid & 3) * 16;
        const float4* pp = reinterpret_cast<const float4*>(pagg + ((size_t)bh*NN + i0 + r)*PHH + c0);
        #pragma unroll
        for (int e = 0; e < 4; e++) {
            float4 t = pp[e];
            Ws_[r][c0+4*e+0]=t.x; Ws_[r][c0+4*e+1]=t.y; Ws_[r][c0+4*e+2]=t.z; Ws_[r][c0+4*e+3]=t.w;
        }
        const float4* sp = reinterpret_cast<const float4*>(Wsv + (size_t)r*DD + c0);
        #pragma unroll
        for (int e = 0; e < 4; e++) {
            float4 t = sp[e];
            Vs[r][c0+4*e+0]=t.x; Vs[r][c0+4*e+1]=t.y; Vs[r][c0+4*e+2]=t.z; Vs[r][c0+4*e+3]=t.w;
        }
    }
    __syncthreads();
    #pragma unroll 4
    for (int ph = 0; ph < 64; ph++) {
        float a[4], bb[4];
        #pragma unroll
        for (int e = 0; e < 4; e++) a[e] = Ws_[ty*4+e][ph];
        *reinterpret_cast<float4*>(bb) = *reinterpret_cast<const float4*>(&Vs[ph][tx*4]);
        #pragma unroll
        for (int i2=0;i2<4;i2++)
            #pragma unroll
            for (int j2=0;j2<4;j2++) acc[i2][j2] = fmaf(a[i2], bb[j2], acc[i2][j2]);
    }
    #pragma unroll
    for (int ii=0;ii<4;ii++){
        const int irow = i0 + ty*4 + ii;
        float4 o;
        o.x = acc[ii][0] + bsv[tx*4+0];
        o.y = acc[ii][1] + bsv[tx*4+1];
        o.z = acc[ii][2] + bsv[tx*4+2];
        o.w = acc[ii][3] + bsv[tx*4+3];
        *reinterpret_cast<float4*>(&attn[((size_t)b*NN + irow)*HSZ + h*DD + tx*4]) = o;
    }
}

// ---------------------------------------------------------------------------
// K5a: tres = nodes + relu(attn @ Wo + bo)
// ---------------------------------------------------------------------------
__global__ __launch_bounds__(256) void k_proj(
    const float* __restrict__ attn, const float* __restrict__ Wo,
    const float* __restrict__ bo, const float* __restrict__ nodes,
    float* __restrict__ tres)
{
    __shared__ float As[16][132];
    __shared__ float Bs[16][132];
    const int row0 = blockIdx.x * 128, col0 = blockIdx.y * 128;
    const int tid = threadIdx.x, tx = tid & 15, ty = tid >> 4;
    float acc[8][8];
    #pragma unroll
    for (int i=0;i<8;i++){
        #pragma unroll
        for (int j=0;j<8;j++) acc[i][j]=0.f;
    }
    for (int k0 = 0; k0 < HSZ; k0 += 16) {
        {
            const int r = tid >> 1, kk = (tid & 1) * 8;
            const float4* ap = reinterpret_cast<const float4*>(attn + (size_t)(row0 + r)*HSZ + k0 + kk);
            float4 a0 = ap[0], a1 = ap[1];
            As[kk+0][r]=a0.x; As[kk+1][r]=a0.y; As[kk+2][r]=a0.z; As[kk+3][r]=a0.w;
            As[kk+4][r]=a1.x; As[kk+5][r]=a1.y; As[kk+6][r]=a1.z; As[kk+7][r]=a1.w;
            const int kb = tid >> 4, c0 = (tid & 15) * 8;
            const float4* bp = reinterpret_cast<const float4*>(Wo + (size_t)(k0+kb)*HSZ + col0 + c0);
            float4 b0 = bp[0], b1 = bp[1];
            Bs[kb][c0+0]=b0.x; Bs[kb][c0+1]=b0.y; Bs[kb][c0+2]=b0.z; Bs[kb][c0+3]=b0.w;
            Bs[kb][c0+4]=b1.x; Bs[kb][c0+5]=b1.y; Bs[kb][c0+6]=b1.z; Bs[kb][c0+7]=b1.w;
        }
        __syncthreads();
        #pragma unroll
        for (int kk = 0; kk < 16; kk++) {
            float a[8], b[8];
            *reinterpret_cast<float4*>(&a[0]) = *reinterpret_cast<const float4*>(&As[kk][ty*8]);
            *reinterpret_cast<float4*>(&a[4]) = *reinterpret_cast<const float4*>(&As[kk][ty*8+4]);
            *reinterpret_cast<float4*>(&b[0]) = *reinterpret_cast<const float4*>(&Bs[kk][tx*8]);
            *reinterpret_cast<float4*>(&b[4]) = *reinterpret_cast<const float4*>(&Bs[kk][tx*8+4]);
            #pragma unroll
            for (int i=0;i<8;i++)
                #pragma unroll
                for (int j=0;j<8;j++) acc[i][j] = fmaf(a[i], b[j], acc[i][j]);
        }
        __syncthreads();
    }
    #pragma unroll
    for (int j=0;j<8;j++){
        const int c = col0 + tx*8 + j;
        const float bov = bo[c];
        #pragma unroll
        for (int i=0;i<8;i++){
            const int rr = row0 + ty*8 + i;
            float val = fmaxf(acc[i][j] + bov, 0.f);
            val += nodes[(size_t)rr*HSZ + c];
            tres[(size_t)rr*HSZ + c] = val;
        }
    }
}

// ---------------------------------------------------------------------------
// K5b: row LayerNorm over 768 -> out0 (f32)
// ---------------------------------------------------------------------------
__global__ __launch_bounds__(256) void k_ln(
    const float* __restrict__ tres, const float* __restrict__ g,
    const float* __restrict__ bta, float* __restrict__ out0)
{
    const int row = blockIdx.x;
    const float* x = tres + (size_t)row * HSZ;
    const int tid = threadIdx.x;
    const int wid = tid >> 6, lane = tid & 63;
    __shared__ float r4[4];
    __shared__ float sc[2];
    float v0 = x[tid], v1 = x[tid+256], v2 = x[tid+512];
    float s = v0 + v1 + v2;
    #pragma unroll
    for (int o = 32; o > 0; o >>= 1) s += __shfl_xor(s, o, 64);
    if (lane == 0) r4[wid] = s;
    __syncthreads();
    if (tid == 0) sc[0] = (r4[0]+r4[1]+r4[2]+r4[3]) * (1.f/768.f);
    __syncthreads();
    const float m = sc[0];
    const float d0 = v0-m, d1 = v1-m, d2 = v2-m;
    float vs = d0*d0 + d1*d1 + d2*d2;
    #pragma unroll
    for (int o = 32; o > 0; o >>= 1) vs += __shfl_xor(vs, o, 64);
    if (lane == 0) r4[wid] = vs;
    __syncthreads();
    if (tid == 0) sc[1] = rsqrtf((r4[0]+r4[1]+r4[2]+r4[3]) * (1.f/768.f) + 1e-5f);
    __syncthreads();
    const float rs = sc[1];
    out0[(size_t)row*HSZ + tid      ] = d0*rs*g[tid      ] + bta[tid      ];
    out0[(size_t)row*HSZ + tid + 256] = d1*rs*g[tid + 256] + bta[tid + 256];
    out0[(size_t)row*HSZ + tid + 512] = d2*rs*g[tid + 512] + bta[tid + 512];
}

// ---------------------------------------------------------------------------
extern "C" void kernel_launch(void* const* d_in, const int* in_sizes, int n_in,
                              void* d_out, int out_size, void* d_ws, size_t ws_size,
                              hipStream_t stream)
{
    (void)in_sizes; (void)n_in; (void)out_size; (void)ws_size;
    const float* nodes = (const float*)d_in[0];
    const float* bias  = (const float*)d_in[1];
    const float* paths = (const float*)d_in[2];
    const float* Wq = (const float*)d_in[3];
    const float* bq = (const float*)d_in[4];
    const float* Wk = (const float*)d_in[5];
    const float* bk = (const float*)d_in[6];
    const float* Wv = (const float*)d_in[7];
    const float* bv = (const float*)d_in[8];
    const float* Wsk= (const float*)d_in[9];
    const float* bsk= (const float*)d_in[10];
    const float* Wsv= (const float*)d_in[11];
    const float* bsv= (const float*)d_in[12];
    const float* Wo = (const float*)d_in[13];
    const float* bo = (const float*)d_in[14];
    const float* lng= (const float*)d_in[15];
    const float* lnb= (const float*)d_in[16];
    const float* plg= (const float*)d_in[17];
    const float* plb= (const float*)d_in[18];

    float* ws   = (float*)d_ws;
    float* q_s  = ws;
    float* kbuf = ws + 2359296;
    float* vbuf = ws + 4718592;
    float* qsk  = ws + 7077888;
    float* qbsk = ws + 9437184;
    float* wc   = ws + 9474048;
    float* attn = q_s;
    float* pagg = kbuf;
    float* tres = wc;

    float* out0 = (float*)d_out;
    float* wout = out0 + (size_t)BB*NN*HSZ;

    hipLaunchKernelGGL(k_qkv,    dim3(24,6,3), dim3(256), 0, stream,
                       nodes, Wq,bq, Wk,bk, Wv,bv, q_s, kbuf, vbuf);
    hipLaunchKernelGGL(k_qsk,    dim3(9216),   dim3(256), 0, stream,
                       q_s, Wsk, bsk, qsk, qbsk);
    hipLaunchKernelGGL(k_scores, dim3(6,6,96), dim3(256), 0, stream,
                       q_s, kbuf, wc);
    hipLaunchKernelGGL(k_soft,   dim3(3072),   dim3(384), 0, stream,
                       paths, bias, plg, plb, wc, qsk, qbsk, pagg, wout);
    hipLaunchKernelGGL(k_av,     dim3(6,96),   dim3(256), 0, stream,
                       wout, vbuf, pagg, Wsv, bsv, attn);
    hipLaunchKernelGGL(k_proj,   dim3(24,6),   dim3(256), 0, stream,
                       attn, Wo, bo, nodes, tres);
    hipLaunchKernelGGL(k_ln,     dim3(3072),   dim3(256), 0, stream,
                       tres, lng, lnb, out0);
}

// Round 7
// 406.036 us; speedup vs baseline: 2.1353x; 1.3486x over previous
//
#include <hip/hip_runtime.h>
#include <hip/hip_bf16.h>

typedef __hip_bfloat16 bf16;
typedef __attribute__((ext_vector_type(8))) short short8b;   // 8 bf16 (MFMA operand)
typedef __attribute__((ext_vector_type(4))) float f32x4;     // MFMA accumulator

#define BB  8
#define NN  384
#define HH  12
#define HSZ 768
#define DD  64
#define PHH 64
#define PSTR 386   // pLNT row stride in u32 words (even: b64-aligned; 2-bank skew)
#define SWS  194   // sw row stride in u32 words (even)

__device__ __forceinline__ float bflo(unsigned u){ union{unsigned q; float f;} c; c.q = u << 16;        return c.f; }
__device__ __forceinline__ float bfhi(unsigned u){ union{unsigned q; float f;} c; c.q = u & 0xffff0000u; return c.f; }

// pack two f32 into a u32 of two RNE-rounded bf16 (lo, hi)
__device__ __forceinline__ unsigned pk2bf(float lo, float hi){
    union{float f; unsigned u;} a, b; a.f = lo; b.f = hi;
    unsigned ua = a.u + 0x7fffu + ((a.u >> 16) & 1u);
    unsigned ub = b.u + 0x7fffu + ((b.u >> 16) & 1u);
    return (ua >> 16) | (ub & 0xffff0000u);
}

union U8 { uint4 u; short8b v; };

// ---------------------------------------------------------------------------
// K1: QKV projection, MFMA bf16.  (validated R6)
// ---------------------------------------------------------------------------
__global__ __launch_bounds__(256) void k_qkv(
    const float* __restrict__ nodes,
    const float* __restrict__ Wq, const float* __restrict__ bq,
    const float* __restrict__ Wk, const float* __restrict__ bk,
    const float* __restrict__ Wv, const float* __restrict__ bv,
    float* __restrict__ oq, float* __restrict__ okk, float* __restrict__ ov)
{
    const int which = blockIdx.z;
    const float* __restrict__ W   = which==0 ? Wq : (which==1 ? Wk : Wv);
    const float* __restrict__ bia = which==0 ? bq : (which==1 ? bk : bv);
    float* __restrict__ out       = which==0 ? oq : (which==1 ? okk : ov);
    const float scale = which==0 ? 0.125f : 1.0f;

    __shared__ __align__(16) unsigned Alds[128*20];
    __shared__ __align__(16) unsigned Blds[128*20];

    const int row0 = blockIdx.x * 128;
    const int col0 = blockIdx.y * 128;
    const int tid  = threadIdx.x;
    const int wv   = tid >> 6, lane = tid & 63;
    const int wm   = wv & 1,  wn   = wv >> 1;
    const int fr   = lane & 15, kg = lane >> 4;

    f32x4 acc[4][4];
    #pragma unroll
    for (int i=0;i<4;i++){
        #pragma unroll
        for (int j=0;j<4;j++){ acc[i][j][0]=0.f; acc[i][j][1]=0.f; acc[i][j][2]=0.f; acc[i][j][3]=0.f; }
    }

    for (int k0 = 0; k0 < HSZ; k0 += 32) {
        {   // stage A
            const int m = tid >> 1, kh = tid & 1;
            const float4* ap = reinterpret_cast<const float4*>(nodes + (size_t)(row0 + m)*HSZ + k0 + kh*16);
            float4 a0 = ap[0], a1 = ap[1], a2 = ap[2], a3 = ap[3];
            uint4 p0, p1;
            p0.x = pk2bf(a0.x,a0.y); p0.y = pk2bf(a0.z,a0.w);
            p0.z = pk2bf(a1.x,a1.y); p0.w = pk2bf(a1.z,a1.w);
            p1.x = pk2bf(a2.x,a2.y); p1.y = pk2bf(a2.z,a2.w);
            p1.z = pk2bf(a3.x,a3.y); p1.w = pk2bf(a3.z,a3.w);
            *reinterpret_cast<uint4*>(&Alds[m*20 + kh*8    ]) = p0;
            *reinterpret_cast<uint4*>(&Alds[m*20 + kh*8 + 4]) = p1;
        }
        {   // stage B (column reads of W)
            const int n = tid & 127, kq = tid >> 7;
            const float* wp = W + (size_t)(k0 + kq*16)*HSZ + col0 + n;
            float x[16];
            #pragma unroll
            for (int j = 0; j < 16; j++) x[j] = wp[(size_t)j*HSZ];
            uint4 p0, p1;
            p0.x = pk2bf(x[0],x[1]);   p0.y = pk2bf(x[2],x[3]);
            p0.z = pk2bf(x[4],x[5]);   p0.w = pk2bf(x[6],x[7]);
            p1.x = pk2bf(x[8],x[9]);   p1.y = pk2bf(x[10],x[11]);
            p1.z = pk2bf(x[12],x[13]); p1.w = pk2bf(x[14],x[15]);
            *reinterpret_cast<uint4*>(&Blds[n*20 + kq*8    ]) = p0;
            *reinterpret_cast<uint4*>(&Blds[n*20 + kq*8 + 4]) = p1;
        }
        __syncthreads();
        U8 au[4], bu[4];
        #pragma unroll
        for (int t = 0; t < 4; t++) {
            au[t].u = *reinterpret_cast<const uint4*>(&Alds[(wm*64 + t*16 + fr)*20 + kg*4]);
            bu[t].u = *reinterpret_cast<const uint4*>(&Blds[(wn*64 + t*16 + fr)*20 + kg*4]);
        }
        #pragma unroll
        for (int mt = 0; mt < 4; mt++)
            #pragma unroll
            for (int nt = 0; nt < 4; nt++)
                acc[mt][nt] = __builtin_amdgcn_mfma_f32_16x16x32_bf16(
                    au[mt].v, bu[nt].v, acc[mt][nt], 0, 0, 0);
        __syncthreads();
    }
    #pragma unroll
    for (int nt = 0; nt < 4; nt++) {
        const int col = col0 + wn*64 + nt*16 + fr;
        const int h = col >> 6, d = col & 63;
        const float bv_ = bia[col];
        #pragma unroll
        for (int mt = 0; mt < 4; mt++) {
            #pragma unroll
            for (int r = 0; r < 4; r++) {
                const int m = row0 + wm*64 + mt*16 + kg*4 + r;
                const int b_ = m / NN, n_ = m % NN;
                out[(((size_t)b_*HH + h)*NN + n_)*DD + d] = (acc[mt][nt][r] + bv_) * scale;
            }
        }
    }
}

// ---------------------------------------------------------------------------
// K1b: qsk[b,h,i,ph] = sum_d Wsk[ph,d]*q_s[b,h,i,d]
// (q.bsk term dropped: constant over j -> cancels in softmax)
// ---------------------------------------------------------------------------
__global__ __launch_bounds__(256) void k_qsk(
    const float* __restrict__ q_s, const float* __restrict__ Wsk,
    float* __restrict__ qsk)
{
    const int lane = threadIdx.x & 63;
    const int row = blockIdx.x * 4 + (threadIdx.x >> 6);
    const float qd = q_s[(size_t)row * DD + lane];
    float acc = 0.f;
    const float* wr = Wsk + lane * DD;
    #pragma unroll 8
    for (int d = 0; d < DD; d++) acc = fmaf(wr[d], __shfl(qd, d, 64), acc);
    qsk[(size_t)row * DD + lane] = acc;
}

// ---------------------------------------------------------------------------
// K2: content scores wc[b,h,i,j] = q . k   (f32), 64x64 tile, 4x4/thread
// ---------------------------------------------------------------------------
__global__ __launch_bounds__(256) void k_scores(
    const float* __restrict__ q_s, const float* __restrict__ kk_, float* __restrict__ wc)
{
    const int bh = blockIdx.z;
    const float* __restrict__ Q = q_s + (size_t)bh * NN * DD;
    const float* __restrict__ K = kk_ + (size_t)bh * NN * DD;
    __shared__ float Qs[64][68];
    __shared__ float Ks[64][68];
    const int tid = threadIdx.x;
    const int i0 = blockIdx.x * 64, j0 = blockIdx.y * 64;
    {
        const int r = tid >> 2, d0 = (tid & 3) * 16;
        const float4* qp = reinterpret_cast<const float4*>(Q + (size_t)(i0 + r) * DD + d0);
        const float4* kp = reinterpret_cast<const float4*>(K + (size_t)(j0 + r) * DD + d0);
        #pragma unroll
        for (int e = 0; e < 4; e++) {
            float4 x = qp[e];
            Qs[d0+4*e+0][r]=x.x; Qs[d0+4*e+1][r]=x.y; Qs[d0+4*e+2][r]=x.z; Qs[d0+4*e+3][r]=x.w;
            float4 y = kp[e];
            Ks[d0+4*e+0][r]=y.x; Ks[d0+4*e+1][r]=y.y; Ks[d0+4*e+2][r]=y.z; Ks[d0+4*e+3][r]=y.w;
        }
    }
    __syncthreads();
    const int tx = tid & 15, ty = tid >> 4;
    float acc[4][4] = {};
    #pragma unroll 4
    for (int d = 0; d < 64; d++) {
        float a[4], b[4];
        *reinterpret_cast<float4*>(a) = *reinterpret_cast<const float4*>(&Qs[d][ty*4]);
        *reinterpret_cast<float4*>(b) = *reinterpret_cast<const float4*>(&Ks[d][tx*4]);
        #pragma unroll
        for (int i=0;i<4;i++)
            #pragma unroll
            for (int j=0;j<4;j++) acc[i][j] = fmaf(a[i], b[j], acc[i][j]);
    }
    #pragma unroll
    for (int i=0;i<4;i++){
        const size_t ro = ((size_t)bh*NN + i0 + ty*4 + i)*NN + j0 + tx*4;
        float4 o; o.x=acc[i][0]; o.y=acc[i][1]; o.z=acc[i][2]; o.w=acc[i][3];
        *reinterpret_cast<float4*>(&wc[ro]) = o;
    }
}

// ---------------------------------------------------------------------------
// K3: fused per-(b,i), MFMA version.
//  phase1: LN paths rows -> pLNT [ph-pair][j] packed bf16 (stride 386 words)
//          + qskA [16h][ph] bf16 A-operand tile
//  phase2: scoresT[h,j] via mfma(qskA, pLNT) ; + wc + bias ; softmax with
//          16-lane-group shuffle reduce + cross-wave LDS combine (2 barriers)
//  phase3: w -> sw [16h][j-pair] bf16 ; pagg[h,ph] via mfma(sw, pLNT-halves)
//  Wave wv owns j in [64wv, 64wv+64) for scores; waves 0-3 own ph-tiles for pagg.
// ---------------------------------------------------------------------------
__global__ __launch_bounds__(384) void k_soft(
    const float* __restrict__ paths, const float* __restrict__ bias,
    const float* __restrict__ pg, const float* __restrict__ pb,
    const float* __restrict__ wc, const float* __restrict__ qsk,
    float* __restrict__ pagg, float* __restrict__ w_out)
{
    const int bi = blockIdx.x;
    const int b = bi / NN, i = bi % NN;
    __shared__ __align__(16) unsigned pLNT[32 * PSTR];  // 49408 B
    __shared__ __align__(16) unsigned sw32[16 * SWS];   // 12416 B
    __shared__ __align__(16) unsigned qskA[16 * 36];    //  2304 B
    __shared__ float redM[6][16];
    __shared__ float redS[6][16];
    __shared__ float pgf[64], pbf[64];
    const int tid  = threadIdx.x;
    const int wv   = tid >> 6, lane = tid & 63;
    const int g    = lane >> 4, c = lane & 15;

    if (tid < 64) { pgf[tid] = pg[tid]; pbf[tid] = pb[tid]; }
    {   // fill qskA: h = tid>>5 (0..11), 2 ph per thread; zero rows 12..15
        const int h = tid >> 5, t2 = tid & 31;
        const size_t r0 = ((size_t)(b*HH + h)*NN + i)*DD;
        const float q0 = qsk[r0 + 2*t2], q1 = qsk[r0 + 2*t2 + 1];
        qskA[h*36 + t2] = pk2bf(q0, q1);
        if (tid < 144) qskA[432 + tid] = 0u;
    }
    __syncthreads();

    {   // LayerNorm of path row j = tid -> pLNT transposed packed
        const float4* src = reinterpret_cast<const float4*>(paths + ((size_t)bi * NN + tid) * PHH);
        float x[64];
        #pragma unroll
        for (int t = 0; t < 16; t++) {
            float4 u = src[t];
            x[4*t]=u.x; x[4*t+1]=u.y; x[4*t+2]=u.z; x[4*t+3]=u.w;
        }
        float m0 = 0.f, m1 = 0.f;
        #pragma unroll
        for (int t = 0; t < 32; t++){ m0 += x[2*t]; m1 += x[2*t+1]; }
        const float m = (m0+m1)*(1.f/64.f);
        float v0 = 0.f, v1 = 0.f;
        #pragma unroll
        for (int t = 0; t < 32; t++){
            float a = x[2*t]-m, d = x[2*t+1]-m;
            v0 = fmaf(a,a,v0); v1 = fmaf(d,d,v1);
        }
        const float rs = rsqrtf((v0+v1)*(1.f/64.f) + 1e-5f);
        #pragma unroll
        for (int w = 0; w < 32; w++){
            const float lo = (x[2*w  ]-m)*rs*pgf[2*w  ] + pbf[2*w  ];
            const float hi = (x[2*w+1]-m)*rs*pgf[2*w+1] + pbf[2*w+1];
            pLNT[w*PSTR + tid] = pk2bf(lo, hi);
        }
    }
    __syncthreads();

    // ---- phase 2: scoresT via MFMA.  D[h = 4g+r][j = 64wv + 16nt + c]
    f32x4 sc[4];
    #pragma unroll
    for (int nt=0;nt<4;nt++){ sc[nt][0]=0.f; sc[nt][1]=0.f; sc[nt][2]=0.f; sc[nt][3]=0.f; }
    const int jbase = wv*64 + c;
    #pragma unroll
    for (int kh = 0; kh < 2; kh++) {
        U8 a; a.u = *reinterpret_cast<const uint4*>(&qskA[c*36 + kh*16 + g*4]);
        #pragma unroll
        for (int nt = 0; nt < 4; nt++) {
            const unsigned* pb_ = &pLNT[(kh*16 + g*4)*PSTR + jbase + nt*16];
            uint4 bw;
            bw.x = pb_[0]; bw.y = pb_[PSTR]; bw.z = pb_[2*PSTR]; bw.w = pb_[3*PSTR];
            U8 bb; bb.u = bw;
            sc[nt] = __builtin_amdgcn_mfma_f32_16x16x32_bf16(a.v, bb.v, sc[nt], 0, 0, 0);
        }
    }
    // add content scores + bias
    {
        #pragma unroll
        for (int nt = 0; nt < 4; nt++) {
            const int j = jbase + nt*16;
            const float bj = bias[b*NN + j];
            #pragma unroll
            for (int r = 0; r < 4; r++) {
                const int h = g*4 + r;
                float add = bj;
                if (h < HH) add += wc[((size_t)(b*HH + h)*NN + i)*NN + j];
                sc[nt][r] += add;
            }
        }
    }
    // softmax: per-head reduce over j (16-lane group + cross-wave LDS)
    float e_[4][4], inv_[4];
    {
        float mr[4];
        #pragma unroll
        for (int r = 0; r < 4; r++) {
            float m2 = fmaxf(fmaxf(sc[0][r], sc[1][r]), fmaxf(sc[2][r], sc[3][r]));
            #pragma unroll
            for (int o = 1; o <= 8; o <<= 1) m2 = fmaxf(m2, __shfl_xor(m2, o, 64));
            mr[r] = m2;
        }
        if (c == 0) {
            #pragma unroll
            for (int r = 0; r < 4; r++) redM[wv][g*4 + r] = mr[r];
        }
        __syncthreads();
        #pragma unroll
        for (int r = 0; r < 4; r++) {
            float Mv = redM[0][g*4 + r];
            #pragma unroll
            for (int w2 = 1; w2 < 6; w2++) Mv = fmaxf(Mv, redM[w2][g*4 + r]);
            float s2 = 0.f;
            #pragma unroll
            for (int nt = 0; nt < 4; nt++){ e_[nt][r] = __expf(sc[nt][r] - Mv); s2 += e_[nt][r]; }
            #pragma unroll
            for (int o = 1; o <= 8; o <<= 1) s2 += __shfl_xor(s2, o, 64);
            mr[r] = s2;
        }
        if (c == 0) {
            #pragma unroll
            for (int r = 0; r < 4; r++) redS[wv][g*4 + r] = mr[r];
        }
        __syncthreads();
        #pragma unroll
        for (int r = 0; r < 4; r++) {
            float Sv = redS[0][g*4 + r];
            #pragma unroll
            for (int w2 = 1; w2 < 6; w2++) Sv += redS[w2][g*4 + r];
            inv_[r] = 1.f / Sv;
        }
    }
    // w: store to global (h<12) + pack into sw (A-operand layout for pagg)
    #pragma unroll
    for (int nt = 0; nt < 4; nt++) {
        const int j = jbase + nt*16;
        #pragma unroll
        for (int r = 0; r < 4; r++) {
            const int h = g*4 + r;
            const float wgt = e_[nt][r] * inv_[r];
            if (h < HH) w_out[((size_t)(b*HH + h)*NN + i)*NN + j] = wgt;
            const float oth = __shfl_xor(wgt, 1, 64);
            if ((c & 1) == 0) sw32[h*SWS + (j >> 1)] = pk2bf(wgt, oth);
        }
    }
    __syncthreads();

    // ---- phase 3: pagg via MFMA.  waves 0..3: ph-tile = 16*wv.
    if (wv < 4) {
        f32x4 pa; pa[0]=0.f; pa[1]=0.f; pa[2]=0.f; pa[3]=0.f;
        const int prow = 8*wv + (c >> 1);     // pLNT pair-row for ph = 16wv + c
        const bool hi = (c & 1);
        #pragma unroll 4
        for (int kt = 0; kt < 12; kt++) {
            // A-frag: w[h = c][j-span = 32kt + 8g .. +8]
            uint2 a0 = *reinterpret_cast<const uint2*>(&sw32[c*SWS + kt*16 + g*4]);
            uint2 a1 = *reinterpret_cast<const uint2*>(&sw32[c*SWS + kt*16 + g*4 + 2]);
            U8 af; af.u.x = a0.x; af.u.y = a0.y; af.u.z = a1.x; af.u.w = a1.y;
            // B-frag: pLN[j-span][ph] = half (c&1) of pLNT[prow][j..j+8]
            const unsigned* pr = &pLNT[prow*PSTR + 32*kt + 8*g];
            uint2 w01 = *reinterpret_cast<const uint2*>(&pr[0]);
            uint2 w23 = *reinterpret_cast<const uint2*>(&pr[2]);
            uint2 w45 = *reinterpret_cast<const uint2*>(&pr[4]);
            uint2 w67 = *reinterpret_cast<const uint2*>(&pr[6]);
            uint4 bw;
            if (hi) {
                bw.x = (w01.x >> 16) | (w01.y & 0xffff0000u);
                bw.y = (w23.x >> 16) | (w23.y & 0xffff0000u);
                bw.z = (w45.x >> 16) | (w45.y & 0xffff0000u);
                bw.w = (w67.x >> 16) | (w67.y & 0xffff0000u);
            } else {
                bw.x = (w01.x & 0xffffu) | (w01.y << 16);
                bw.y = (w23.x & 0xffffu) | (w23.y << 16);
                bw.z = (w45.x & 0xffffu) | (w45.y << 16);
                bw.w = (w67.x & 0xffffu) | (w67.y << 16);
            }
            U8 bf_; bf_.u = bw;
            pa = __builtin_amdgcn_mfma_f32_16x16x32_bf16(af.v, bf_.v, pa, 0, 0, 0);
        }
        #pragma unroll
        for (int r = 0; r < 4; r++) {
            const int h = g*4 + r;
            if (h < HH)
                pagg[((size_t)(b*HH + h)*NN + i)*DD + 16*wv + c] = pa[r];
        }
    }
}

// ---------------------------------------------------------------------------
// K4: attn = w@v + pagg@Wsv + bsv   per (b,h), 64-row tiles  (f32 VALU)
// ---------------------------------------------------------------------------
__global__ __launch_bounds__(256) void k_av(
    const float* __restrict__ w, const float* __restrict__ v_,
    const float* __restrict__ pagg, const float* __restrict__ Wsv,
    const float* __restrict__ bsv, float* __restrict__ attn)
{
    const int bh = blockIdx.y;
    const int b = bh / HH, h = bh % HH;
    const int i0 = blockIdx.x * 64;
    __shared__ float Ws_[64][68];
    __shared__ float Vs[64][68];
    const int tid = threadIdx.x;
    const int tx = tid & 15, ty = tid >> 4;
    float acc[4][4] = {};
    for (int j0 = 0; j0 < NN; j0 += 64) {
        {
            const int r = tid >> 2, c0 = (tid & 3) * 16;
            const float4* wp = reinterpret_cast<const float4*>(w + ((size_t)bh*NN + i0 + r)*NN + j0 + c0);
            #pragma unroll
            for (int e = 0; e < 4; e++) {
                float4 t = wp[e];
                Ws_[r][c0+4*e+0]=t.x; Ws_[r][c0+4*e+1]=t.y; Ws_[r][c0+4*e+2]=t.z; Ws_[r][c0+4*e+3]=t.w;
            }
            const float4* vp = reinterpret_cast<const float4*>(v_ + ((size_t)bh*NN + j0 + r)*DD + c0);
            #pragma unroll
            for (int e = 0; e < 4; e++) {
                float4 t = vp[e];
                Vs[r][c0+4*e+0]=t.x; Vs[r][c0+4*e+1]=t.y; Vs[r][c0+4*e+2]=t.z; Vs[r][c0+4*e+3]=t.w;
            }
        }
        __syncthreads();
        #pragma unroll 4
        for (int jj = 0; jj < 64; jj++) {
            float a[4], bb[4];
            #pragma unroll
            for (int e = 0; e < 4; e++) a[e] = Ws_[ty*4+e][jj];
            *reinterpret_cast<float4*>(bb) = *reinterpret_cast<const float4*>(&Vs[jj][tx*4]);
            #pragma unroll
            for (int i2=0;i2<4;i2++)
                #pragma unroll
                for (int j2=0;j2<4;j2++) acc[i2][j2] = fmaf(a[i2], bb[j2], acc[i2][j2]);
        }
        __syncthreads();
    }
    {
        const int r = tid >> 2, c0 = (tid & 3) * 16;
        const float4* pp = reinterpret_cast<const float4*>(pagg + ((size_t)bh*NN + i0 + r)*PHH + c0);
        #pragma unroll
        for (int e = 0; e < 4; e++) {
            float4 t = pp[e];
            Ws_[r][c0+4*e+0]=t.x; Ws_[r][c0+4*e+1]=t.y; Ws_[r][c0+4*e+2]=t.z; Ws_[r][c0+4*e+3]=t.w;
        }
        const float4* sp = reinterpret_cast<const float4*>(Wsv + (size_t)r*DD + c0);
        #pragma unroll
        for (int e = 0; e < 4; e++) {
            float4 t = sp[e];
            Vs[r][c0+4*e+0]=t.x; Vs[r][c0+4*e+1]=t.y; Vs[r][c0+4*e+2]=t.z; Vs[r][c0+4*e+3]=t.w;
        }
    }
    __syncthreads();
    #pragma unroll 4
    for (int ph = 0; ph < 64; ph++) {
        float a[4], bb[4];
        #pragma unroll
        for (int e = 0; e < 4; e++) a[e] = Ws_[ty*4+e][ph];
        *reinterpret_cast<float4*>(bb) = *reinterpret_cast<const float4*>(&Vs[ph][tx*4]);
        #pragma unroll
        for (int i2=0;i2<4;i2++)
            #pragma unroll
            for (int j2=0;j2<4;j2++) acc[i2][j2] = fmaf(a[i2], bb[j2], acc[i2][j2]);
    }
    #pragma unroll
    for (int ii=0;ii<4;ii++){
        const int irow = i0 + ty*4 + ii;
        float4 o;
        o.x = acc[ii][0] + bsv[tx*4+0];
        o.y = acc[ii][1] + bsv[tx*4+1];
        o.z = acc[ii][2] + bsv[tx*4+2];
        o.w = acc[ii][3] + bsv[tx*4+3];
        *reinterpret_cast<float4*>(&attn[((size_t)b*NN + irow)*HSZ + h*DD + tx*4]) = o;
    }
}

// ---------------------------------------------------------------------------
// K5a: tres = nodes + relu(attn @ Wo + bo)   -- MFMA clone of k_qkv
// ---------------------------------------------------------------------------
__global__ __launch_bounds__(256) void k_proj(
    const float* __restrict__ attn, const float* __restrict__ Wo,
    const float* __restrict__ bo, const float* __restrict__ nodes,
    float* __restrict__ tres)
{
    __shared__ __align__(16) unsigned Alds[128*20];
    __shared__ __align__(16) unsigned Blds[128*20];

    const int row0 = blockIdx.x * 128;
    const int col0 = blockIdx.y * 128;
    const int tid  = threadIdx.x;
    const int wv   = tid >> 6, lane = tid & 63;
    const int wm   = wv & 1,  wn   = wv >> 1;
    const int fr   = lane & 15, kg = lane >> 4;

    f32x4 acc[4][4];
    #pragma unroll
    for (int i=0;i<4;i++){
        #pragma unroll
        for (int j=0;j<4;j++){ acc[i][j][0]=0.f; acc[i][j][1]=0.f; acc[i][j][2]=0.f; acc[i][j][3]=0.f; }
    }

    for (int k0 = 0; k0 < HSZ; k0 += 32) {
        {
            const int m = tid >> 1, kh = tid & 1;
            const float4* ap = reinterpret_cast<const float4*>(attn + (size_t)(row0 + m)*HSZ + k0 + kh*16);
            float4 a0 = ap[0], a1 = ap[1], a2 = ap[2], a3 = ap[3];
            uint4 p0, p1;
            p0.x = pk2bf(a0.x,a0.y); p0.y = pk2bf(a0.z,a0.w);
            p0.z = pk2bf(a1.x,a1.y); p0.w = pk2bf(a1.z,a1.w);
            p1.x = pk2bf(a2.x,a2.y); p1.y = pk2bf(a2.z,a2.w);
            p1.z = pk2bf(a3.x,a3.y); p1.w = pk2bf(a3.z,a3.w);
            *reinterpret_cast<uint4*>(&Alds[m*20 + kh*8    ]) = p0;
            *reinterpret_cast<uint4*>(&Alds[m*20 + kh*8 + 4]) = p1;
        }
        {
            const int n = tid & 127, kq = tid >> 7;
            const float* wp = Wo + (size_t)(k0 + kq*16)*HSZ + col0 + n;
            float x[16];
            #pragma unroll
            for (int j = 0; j < 16; j++) x[j] = wp[(size_t)j*HSZ];
            uint4 p0, p1;
            p0.x = pk2bf(x[0],x[1]);   p0.y = pk2bf(x[2],x[3]);
            p0.z = pk2bf(x[4],x[5]);   p0.w = pk2bf(x[6],x[7]);
            p1.x = pk2bf(x[8],x[9]);   p1.y = pk2bf(x[10],x[11]);
            p1.z = pk2bf(x[12],x[13]); p1.w = pk2bf(x[14],x[15]);
            *reinterpret_cast<uint4*>(&Blds[n*20 + kq*8    ]) = p0;
            *reinterpret_cast<uint4*>(&Blds[n*20 + kq*8 + 4]) = p1;
        }
        __syncthreads();
        U8 au[4], bu[4];
        #pragma unroll
        for (int t = 0; t < 4; t++) {
            au[t].u = *reinterpret_cast<const uint4*>(&Alds[(wm*64 + t*16 + fr)*20 + kg*4]);
            bu[t].u = *reinterpret_cast<const uint4*>(&Blds[(wn*64 + t*16 + fr)*20 + kg*4]);
        }
        #pragma unroll
        for (int mt = 0; mt < 4; mt++)
            #pragma unroll
            for (int nt = 0; nt < 4; nt++)
                acc[mt][nt] = __builtin_amdgcn_mfma_f32_16x16x32_bf16(
                    au[mt].v, bu[nt].v, acc[mt][nt], 0, 0, 0);
        __syncthreads();
    }
    #pragma unroll
    for (int nt = 0; nt < 4; nt++) {
        const int col = col0 + wn*64 + nt*16 + fr;
        const float bov = bo[col];
        #pragma unroll
        for (int mt = 0; mt < 4; mt++) {
            #pragma unroll
            for (int r = 0; r < 4; r++) {
                const int m = row0 + wm*64 + mt*16 + kg*4 + r;
                const float val = fmaxf(acc[mt][nt][r] + bov, 0.f) + nodes[(size_t)m*HSZ + col];
                tres[(size_t)m*HSZ + col] = val;
            }
        }
    }
}

// ---------------------------------------------------------------------------
// K5b: row LayerNorm over 768 -> out0 (f32)
// ---------------------------------------------------------------------------
__global__ __launch_bounds__(256) void k_ln(
    const float* __restrict__ tres, const float* __restrict__ g,
    const float* __restrict__ bta, float* __restrict__ out0)
{
    const int row = blockIdx.x;
    const float* x = tres + (size_t)row * HSZ;
    const int tid = threadIdx.x;
    const int wid = tid >> 6, lane = tid & 63;
    __shared__ float r4[4];
    __shared__ float sc[2];
    float v0 = x[tid], v1 = x[tid+256], v2 = x[tid+512];
    float s = v0 + v1 + v2;
    #pragma unroll
    for (int o = 32; o > 0; o >>= 1) s += __shfl_xor(s, o, 64);
    if (lane == 0) r4[wid] = s;
    __syncthreads();
    if (tid == 0) sc[0] = (r4[0]+r4[1]+r4[2]+r4[3]) * (1.f/768.f);
    __syncthreads();
    const float m = sc[0];
    const float d0 = v0-m, d1 = v1-m, d2 = v2-m;
    float vs = d0*d0 + d1*d1 + d2*d2;
    #pragma unroll
    for (int o = 32; o > 0; o >>= 1) vs += __shfl_xor(vs, o, 64);
    if (lane == 0) r4[wid] = vs;
    __syncthreads();
    if (tid == 0) sc[1] = rsqrtf((r4[0]+r4[1]+r4[2]+r4[3]) * (1.f/768.f) + 1e-5f);
    __syncthreads();
    const float rs = sc[1];
    out0[(size_t)row*HSZ + tid      ] = d0*rs*g[tid      ] + bta[tid      ];
    out0[(size_t)row*HSZ + tid + 256] = d1*rs*g[tid + 256] + bta[tid + 256];
    out0[(size_t)row*HSZ + tid + 512] = d2*rs*g[tid + 512] + bta[tid + 512];
}

// ---------------------------------------------------------------------------
extern "C" void kernel_launch(void* const* d_in, const int* in_sizes, int n_in,
                              void* d_out, int out_size, void* d_ws, size_t ws_size,
                              hipStream_t stream)
{
    (void)in_sizes; (void)n_in; (void)out_size; (void)ws_size;
    const float* nodes = (const float*)d_in[0];
    const float* bias  = (const float*)d_in[1];
    const float* paths = (const float*)d_in[2];
    const float* Wq = (const float*)d_in[3];
    const float* bq = (const float*)d_in[4];
    const float* Wk = (const float*)d_in[5];
    const float* bk = (const float*)d_in[6];
    const float* Wv = (const float*)d_in[7];
    const float* bv = (const float*)d_in[8];
    const float* Wsk= (const float*)d_in[9];
    const float* Wsv= (const float*)d_in[11];
    const float* bsv= (const float*)d_in[12];
    const float* Wo = (const float*)d_in[13];
    const float* bo = (const float*)d_in[14];
    const float* lng= (const float*)d_in[15];
    const float* lnb= (const float*)d_in[16];
    const float* plg= (const float*)d_in[17];
    const float* plb= (const float*)d_in[18];

    float* ws   = (float*)d_ws;
    float* q_s  = ws;
    float* kbuf = ws + 2359296;
    float* vbuf = ws + 4718592;
    float* qsk  = ws + 7077888;
    float* wc   = ws + 9474048;
    float* attn = q_s;
    float* pagg = kbuf;
    float* tres = wc;

    float* out0 = (float*)d_out;
    float* wout = out0 + (size_t)BB*NN*HSZ;

    hipLaunchKernelGGL(k_qkv,    dim3(24,6,3), dim3(256), 0, stream,
                       nodes, Wq,bq, Wk,bk, Wv,bv, q_s, kbuf, vbuf);
    hipLaunchKernelGGL(k_qsk,    dim3(9216),   dim3(256), 0, stream,
                       q_s, Wsk, qsk);
    hipLaunchKernelGGL(k_scores, dim3(6,6,96), dim3(256), 0, stream,
                       q_s, kbuf, wc);
    hipLaunchKernelGGL(k_soft,   dim3(3072),   dim3(384), 0, stream,
                       paths, bias, plg, plb, wc, qsk, pagg, wout);
    hipLaunchKernelGGL(k_av,     dim3(6,96),   dim3(256), 0, stream,
                       wout, vbuf, pagg, Wsv, bsv, attn);
    hipLaunchKernelGGL(k_proj,   dim3(24,6),   dim3(256), 0, stream,
                       attn, Wo, bo, nodes, tres);
    hipLaunchKernelGGL(k_ln,     dim3(3072),   dim3(256), 0, stream,
                       tres, lng, lnb, out0);
}

// Round 9
// 345.692 us; speedup vs baseline: 2.5080x; 1.1746x over previous
//
#include <hip/hip_runtime.h>
#include <hip/hip_bf16.h>

typedef __hip_bfloat16 bf16;
typedef __attribute__((ext_vector_type(8))) short short8b;   // 8 bf16 (MFMA operand)
typedef __attribute__((ext_vector_type(4))) float f32x4;     // MFMA accumulator

#define BB  8
#define NN  384
#define HH  12
#define HSZ 768
#define DD  64
#define PHH 64
#define PSTR 386   // pLNT row stride in u32 words
#define SWS  194   // sw row stride in u32 words

__device__ __forceinline__ float bflo(unsigned u){ union{unsigned q; float f;} c; c.q = u << 16;        return c.f; }
__device__ __forceinline__ float bfhi(unsigned u){ union{unsigned q; float f;} c; c.q = u & 0xffff0000u; return c.f; }

// pack two f32 into a u32 of two RNE-rounded bf16 (lo, hi)
__device__ __forceinline__ unsigned pk2bf(float lo, float hi){
    union{float f; unsigned u;} a, b; a.f = lo; b.f = hi;
    unsigned ua = a.u + 0x7fffu + ((a.u >> 16) & 1u);
    unsigned ub = b.u + 0x7fffu + ((b.u >> 16) & 1u);
    return (ua >> 16) | (ub & 0xffff0000u);
}

union U8 { uint4 u; short8b v; };

// pack 8 consecutive float4 (32 f32) into 4 uint4 (16 bf16-pair words)
__device__ __forceinline__ void pk32(const float4* p, uint4* o){
    #pragma unroll
    for (int e = 0; e < 4; e++) {
        float4 x = p[2*e], y = p[2*e+1];
        o[e].x = pk2bf(x.x, x.y); o[e].y = pk2bf(x.z, x.w);
        o[e].z = pk2bf(y.x, y.y); o[e].w = pk2bf(y.z, y.w);
    }
}

// ---------------------------------------------------------------------------
// K1: QKV projection, MFMA bf16.  (validated R6/R7)
// ---------------------------------------------------------------------------
__global__ __launch_bounds__(256) void k_qkv(
    const float* __restrict__ nodes,
    const float* __restrict__ Wq, const float* __restrict__ bq,
    const float* __restrict__ Wk, const float* __restrict__ bk,
    const float* __restrict__ Wv, const float* __restrict__ bv,
    float* __restrict__ oq, float* __restrict__ okk, float* __restrict__ ov)
{
    const int which = blockIdx.z;
    const float* __restrict__ W   = which==0 ? Wq : (which==1 ? Wk : Wv);
    const float* __restrict__ bia = which==0 ? bq : (which==1 ? bk : bv);
    float* __restrict__ out       = which==0 ? oq : (which==1 ? okk : ov);
    const float scale = which==0 ? 0.125f : 1.0f;

    __shared__ __align__(16) unsigned Alds[128*20];
    __shared__ __align__(16) unsigned Blds[128*20];

    const int row0 = blockIdx.x * 128;
    const int col0 = blockIdx.y * 128;
    const int tid  = threadIdx.x;
    const int wv   = tid >> 6, lane = tid & 63;
    const int wm   = wv & 1,  wn   = wv >> 1;
    const int fr   = lane & 15, kg = lane >> 4;

    f32x4 acc[4][4];
    #pragma unroll
    for (int i=0;i<4;i++){
        #pragma unroll
        for (int j=0;j<4;j++){ acc[i][j][0]=0.f; acc[i][j][1]=0.f; acc[i][j][2]=0.f; acc[i][j][3]=0.f; }
    }

    for (int k0 = 0; k0 < HSZ; k0 += 32) {
        {   // stage A: row m, k-half kh (16 f32 -> 8 words); 2 thr/row, BK=32
            const int m = tid >> 1, kh = tid & 1;
            const float4* ap = reinterpret_cast<const float4*>(nodes + (size_t)(row0 + m)*HSZ + k0 + kh*16);
            float4 a0 = ap[0], a1 = ap[1], a2 = ap[2], a3 = ap[3];
            uint4 p0, p1;
            p0.x = pk2bf(a0.x,a0.y); p0.y = pk2bf(a0.z,a0.w);
            p0.z = pk2bf(a1.x,a1.y); p0.w = pk2bf(a1.z,a1.w);
            p1.x = pk2bf(a2.x,a2.y); p1.y = pk2bf(a2.z,a2.w);
            p1.z = pk2bf(a3.x,a3.y); p1.w = pk2bf(a3.z,a3.w);
            *reinterpret_cast<uint4*>(&Alds[m*20 + kh*8    ]) = p0;
            *reinterpret_cast<uint4*>(&Alds[m*20 + kh*8 + 4]) = p1;
        }
        {   // stage B (column reads of W)
            const int n = tid & 127, kq = tid >> 7;
            const float* wp = W + (size_t)(k0 + kq*16)*HSZ + col0 + n;
            float x[16];
            #pragma unroll
            for (int j = 0; j < 16; j++) x[j] = wp[(size_t)j*HSZ];
            uint4 p0, p1;
            p0.x = pk2bf(x[0],x[1]);   p0.y = pk2bf(x[2],x[3]);
            p0.z = pk2bf(x[4],x[5]);   p0.w = pk2bf(x[6],x[7]);
            p1.x = pk2bf(x[8],x[9]);   p1.y = pk2bf(x[10],x[11]);
            p1.z = pk2bf(x[12],x[13]); p1.w = pk2bf(x[14],x[15]);
            *reinterpret_cast<uint4*>(&Blds[n*20 + kq*8    ]) = p0;
            *reinterpret_cast<uint4*>(&Blds[n*20 + kq*8 + 4]) = p1;
        }
        __syncthreads();
        U8 au[4], bu[4];
        #pragma unroll
        for (int t = 0; t < 4; t++) {
            au[t].u = *reinterpret_cast<const uint4*>(&Alds[(wm*64 + t*16 + fr)*20 + kg*4]);
            bu[t].u = *reinterpret_cast<const uint4*>(&Blds[(wn*64 + t*16 + fr)*20 + kg*4]);
        }
        #pragma unroll
        for (int mt = 0; mt < 4; mt++)
            #pragma unroll
            for (int nt = 0; nt < 4; nt++)
                acc[mt][nt] = __builtin_amdgcn_mfma_f32_16x16x32_bf16(
                    au[mt].v, bu[nt].v, acc[mt][nt], 0, 0, 0);
        __syncthreads();
    }
    #pragma unroll
    for (int nt = 0; nt < 4; nt++) {
        const int col = col0 + wn*64 + nt*16 + fr;
        const int h = col >> 6, d = col & 63;
        const float bv_ = bia[col];
        #pragma unroll
        for (int mt = 0; mt < 4; mt++) {
            #pragma unroll
            for (int r = 0; r < 4; r++) {
                const int m = row0 + wm*64 + mt*16 + kg*4 + r;
                const int b_ = m / NN, n_ = m % NN;
                out[(((size_t)b_*HH + h)*NN + n_)*DD + d] = (acc[mt][nt][r] + bv_) * scale;
            }
        }
    }
}

// ---------------------------------------------------------------------------
// K1b: qsk[b,h,i,ph] = sum_d Wsk[ph,d]*q_s[b,h,i,d]
// ---------------------------------------------------------------------------
__global__ __launch_bounds__(256) void k_qsk(
    const float* __restrict__ q_s, const float* __restrict__ Wsk,
    float* __restrict__ qsk)
{
    const int lane = threadIdx.x & 63;
    const int row = blockIdx.x * 4 + (threadIdx.x >> 6);
    const float qd = q_s[(size_t)row * DD + lane];
    float acc = 0.f;
    const float* wr = Wsk + lane * DD;
    #pragma unroll 8
    for (int d = 0; d < DD; d++) acc = fmaf(wr[d], __shfl(qd, d, 64), acc);
    qsk[(size_t)row * DD + lane] = acc;
}

// ---------------------------------------------------------------------------
// K2: content scores, MFMA bf16.  wc[bh][i][j] = q[i,:].k[j,:]
// Grid (3,3,96), 128x128 tile, K=64 one-shot.  FIXED R9: each staging thread
// reads 32 f32 (8xfloat4) and writes 16 words -> full 32-word rows.
// ---------------------------------------------------------------------------
__global__ __launch_bounds__(256) void k_scores(
    const float* __restrict__ q_s, const float* __restrict__ kk_, float* __restrict__ wc)
{
    const int bh = blockIdx.z;
    __shared__ __align__(16) unsigned Alds[128*36];
    __shared__ __align__(16) unsigned Blds[128*36];
    const int i0 = blockIdx.x * 128, j0 = blockIdx.y * 128;
    const int tid = threadIdx.x;
    const int wv  = tid >> 6, lane = tid & 63;
    const int wm  = wv & 1,  wn   = wv >> 1;
    const int fr  = lane & 15, kg = lane >> 4;

    {   // stage: row m = tid>>1, half kh = tid&1 -> 32 f32 = 16 words each
        const int m = tid >> 1, kh = tid & 1;
        const float4* ap = reinterpret_cast<const float4*>(q_s + ((size_t)bh*NN + i0 + m)*DD + kh*32);
        const float4* bp = reinterpret_cast<const float4*>(kk_ + ((size_t)bh*NN + j0 + m)*DD + kh*32);
        uint4 pa[4], pbq[4];
        pk32(ap, pa);
        pk32(bp, pbq);
        #pragma unroll
        for (int e = 0; e < 4; e++) {
            *reinterpret_cast<uint4*>(&Alds[m*36 + kh*16 + 4*e]) = pa[e];
            *reinterpret_cast<uint4*>(&Blds[m*36 + kh*16 + 4*e]) = pbq[e];
        }
    }
    __syncthreads();

    f32x4 acc[4][4];
    #pragma unroll
    for (int i=0;i<4;i++){
        #pragma unroll
        for (int j=0;j<4;j++){ acc[i][j][0]=0.f; acc[i][j][1]=0.f; acc[i][j][2]=0.f; acc[i][j][3]=0.f; }
    }
    #pragma unroll
    for (int ks = 0; ks < 2; ks++) {
        U8 au[4], bu[4];
        #pragma unroll
        for (int t = 0; t < 4; t++) {
            au[t].u = *reinterpret_cast<const uint4*>(&Alds[(wm*64 + t*16 + fr)*36 + ks*16 + kg*4]);
            bu[t].u = *reinterpret_cast<const uint4*>(&Blds[(wn*64 + t*16 + fr)*36 + ks*16 + kg*4]);
        }
        #pragma unroll
        for (int mt = 0; mt < 4; mt++)
            #pragma unroll
            for (int nt = 0; nt < 4; nt++)
                acc[mt][nt] = __builtin_amdgcn_mfma_f32_16x16x32_bf16(
                    au[mt].v, bu[nt].v, acc[mt][nt], 0, 0, 0);
    }
    #pragma unroll
    for (int nt = 0; nt < 4; nt++) {
        const int j = j0 + wn*64 + nt*16 + fr;
        #pragma unroll
        for (int mt = 0; mt < 4; mt++) {
            #pragma unroll
            for (int r = 0; r < 4; r++) {
                const int i = i0 + wm*64 + mt*16 + kg*4 + r;
                wc[((size_t)bh*NN + i)*NN + j] = acc[mt][nt][r];
            }
        }
    }
}

// ---------------------------------------------------------------------------
// K3: fused per-(b,i), MFMA scores + pagg.  (R7 structure + hoisted loads)
// ---------------------------------------------------------------------------
__global__ __launch_bounds__(384) void k_soft(
    const float* __restrict__ paths, const float* __restrict__ bias,
    const float* __restrict__ pg, const float* __restrict__ pb,
    const float* __restrict__ wc, const float* __restrict__ qsk,
    float* __restrict__ pagg, float* __restrict__ w_out)
{
    const int bi = blockIdx.x;
    const int b = bi / NN, i = bi % NN;
    __shared__ __align__(16) unsigned pLNT[32 * PSTR];
    __shared__ __align__(16) unsigned sw32[16 * SWS];
    __shared__ __align__(16) unsigned qskA[16 * 36];
    __shared__ float redM[6][16];
    __shared__ float redS[6][16];
    __shared__ float pgf[64], pbf[64];
    const int tid  = threadIdx.x;
    const int wv   = tid >> 6, lane = tid & 63;
    const int g    = lane >> 4, c = lane & 15;
    const int jbase = wv*64 + c;

    // hoisted phase-2 operands (latency hides under paths-load + LN)
    float wcv[4][4], biasj[4];
    #pragma unroll
    for (int nt = 0; nt < 4; nt++) {
        const int j = jbase + nt*16;
        biasj[nt] = bias[b*NN + j];
        #pragma unroll
        for (int r = 0; r < 4; r++) {
            const int h = g*4 + r;
            wcv[nt][r] = (h < HH) ? wc[((size_t)(b*HH + h)*NN + i)*NN + j] : 0.f;
        }
    }

    if (tid < 64) { pgf[tid] = pg[tid]; pbf[tid] = pb[tid]; }
    {   // fill qskA: h = tid>>5 (0..11), 2 ph per thread; zero rows 12..15
        const int h = tid >> 5, t2 = tid & 31;
        const size_t r0 = ((size_t)(b*HH + h)*NN + i)*DD;
        const float q0 = qsk[r0 + 2*t2], q1 = qsk[r0 + 2*t2 + 1];
        qskA[h*36 + t2] = pk2bf(q0, q1);
        if (tid < 144) qskA[432 + tid] = 0u;
    }
    __syncthreads();

    {   // LayerNorm of path row j = tid -> pLNT transposed packed
        const float4* src = reinterpret_cast<const float4*>(paths + ((size_t)bi * NN + tid) * PHH);
        float x[64];
        #pragma unroll
        for (int t = 0; t < 16; t++) {
            float4 u = src[t];
            x[4*t]=u.x; x[4*t+1]=u.y; x[4*t+2]=u.z; x[4*t+3]=u.w;
        }
        float m0 = 0.f, m1 = 0.f;
        #pragma unroll
        for (int t = 0; t < 32; t++){ m0 += x[2*t]; m1 += x[2*t+1]; }
        const float m = (m0+m1)*(1.f/64.f);
        float v0 = 0.f, v1 = 0.f;
        #pragma unroll
        for (int t = 0; t < 32; t++){
            float a = x[2*t]-m, d = x[2*t+1]-m;
            v0 = fmaf(a,a,v0); v1 = fmaf(d,d,v1);
        }
        const float rs = rsqrtf((v0+v1)*(1.f/64.f) + 1e-5f);
        #pragma unroll
        for (int w = 0; w < 32; w++){
            const float lo = (x[2*w  ]-m)*rs*pgf[2*w  ] + pbf[2*w  ];
            const float hi = (x[2*w+1]-m)*rs*pgf[2*w+1] + pbf[2*w+1];
            pLNT[w*PSTR + tid] = pk2bf(lo, hi);
        }
    }
    __syncthreads();

    // ---- phase 2: scoresT via MFMA.  D[h = 4g+r][j = 64wv + 16nt + c]
    f32x4 sc[4];
    #pragma unroll
    for (int nt=0;nt<4;nt++){ sc[nt][0]=0.f; sc[nt][1]=0.f; sc[nt][2]=0.f; sc[nt][3]=0.f; }
    #pragma unroll
    for (int kh = 0; kh < 2; kh++) {
        U8 a; a.u = *reinterpret_cast<const uint4*>(&qskA[c*36 + kh*16 + g*4]);
        #pragma unroll
        for (int nt = 0; nt < 4; nt++) {
            const unsigned* pb_ = &pLNT[(kh*16 + g*4)*PSTR + jbase + nt*16];
            uint4 bw;
            bw.x = pb_[0]; bw.y = pb_[PSTR]; bw.z = pb_[2*PSTR]; bw.w = pb_[3*PSTR];
            U8 bb; bb.u = bw;
            sc[nt] = __builtin_amdgcn_mfma_f32_16x16x32_bf16(a.v, bb.v, sc[nt], 0, 0, 0);
        }
    }
    #pragma unroll
    for (int nt = 0; nt < 4; nt++)
        #pragma unroll
        for (int r = 0; r < 4; r++)
            sc[nt][r] += wcv[nt][r] + biasj[nt];

    // softmax: per-head reduce over j (16-lane group + cross-wave LDS)
    float e_[4][4], inv_[4];
    {
        float mr[4];
        #pragma unroll
        for (int r = 0; r < 4; r++) {
            float m2 = fmaxf(fmaxf(sc[0][r], sc[1][r]), fmaxf(sc[2][r], sc[3][r]));
            #pragma unroll
            for (int o = 1; o <= 8; o <<= 1) m2 = fmaxf(m2, __shfl_xor(m2, o, 64));
            mr[r] = m2;
        }
        if (c == 0) {
            #pragma unroll
            for (int r = 0; r < 4; r++) redM[wv][g*4 + r] = mr[r];
        }
        __syncthreads();
        #pragma unroll
        for (int r = 0; r < 4; r++) {
            float Mv = redM[0][g*4 + r];
            #pragma unroll
            for (int w2 = 1; w2 < 6; w2++) Mv = fmaxf(Mv, redM[w2][g*4 + r]);
            float s2 = 0.f;
            #pragma unroll
            for (int nt = 0; nt < 4; nt++){ e_[nt][r] = __expf(sc[nt][r] - Mv); s2 += e_[nt][r]; }
            #pragma unroll
            for (int o = 1; o <= 8; o <<= 1) s2 += __shfl_xor(s2, o, 64);
            mr[r] = s2;
        }
        if (c == 0) {
            #pragma unroll
            for (int r = 0; r < 4; r++) redS[wv][g*4 + r] = mr[r];
        }
        __syncthreads();
        #pragma unroll
        for (int r = 0; r < 4; r++) {
            float Sv = redS[0][g*4 + r];
            #pragma unroll
            for (int w2 = 1; w2 < 6; w2++) Sv += redS[w2][g*4 + r];
            inv_[r] = 1.f / Sv;
        }
    }
    // w: store to global (h<12) + pack into sw (A-operand layout for pagg)
    #pragma unroll
    for (int nt = 0; nt < 4; nt++) {
        const int j = jbase + nt*16;
        #pragma unroll
        for (int r = 0; r < 4; r++) {
            const int h = g*4 + r;
            const float wgt = e_[nt][r] * inv_[r];
            if (h < HH) w_out[((size_t)(b*HH + h)*NN + i)*NN + j] = wgt;
            const float oth = __shfl_xor(wgt, 1, 64);
            if ((c & 1) == 0) sw32[h*SWS + (j >> 1)] = pk2bf(wgt, oth);
        }
    }
    __syncthreads();

    // ---- phase 3: pagg via MFMA.  waves 0..3: ph-tile = 16*wv.
    if (wv < 4) {
        f32x4 pa; pa[0]=0.f; pa[1]=0.f; pa[2]=0.f; pa[3]=0.f;
        const int prow = 8*wv + (c >> 1);
        const bool hi = (c & 1);
        #pragma unroll 4
        for (int kt = 0; kt < 12; kt++) {
            uint2 a0 = *reinterpret_cast<const uint2*>(&sw32[c*SWS + kt*16 + g*4]);
            uint2 a1 = *reinterpret_cast<const uint2*>(&sw32[c*SWS + kt*16 + g*4 + 2]);
            U8 af; af.u.x = a0.x; af.u.y = a0.y; af.u.z = a1.x; af.u.w = a1.y;
            const unsigned* pr = &pLNT[prow*PSTR + 32*kt + 8*g];
            uint2 w01 = *reinterpret_cast<const uint2*>(&pr[0]);
            uint2 w23 = *reinterpret_cast<const uint2*>(&pr[2]);
            uint2 w45 = *reinterpret_cast<const uint2*>(&pr[4]);
            uint2 w67 = *reinterpret_cast<const uint2*>(&pr[6]);
            uint4 bw;
            if (hi) {
                bw.x = (w01.x >> 16) | (w01.y & 0xffff0000u);
                bw.y = (w23.x >> 16) | (w23.y & 0xffff0000u);
                bw.z = (w45.x >> 16) | (w45.y & 0xffff0000u);
                bw.w = (w67.x >> 16) | (w67.y & 0xffff0000u);
            } else {
                bw.x = (w01.x & 0xffffu) | (w01.y << 16);
                bw.y = (w23.x & 0xffffu) | (w23.y << 16);
                bw.z = (w45.x & 0xffffu) | (w45.y << 16);
                bw.w = (w67.x & 0xffffu) | (w67.y << 16);
            }
            U8 bf_; bf_.u = bw;
            pa = __builtin_amdgcn_mfma_f32_16x16x32_bf16(af.v, bf_.v, pa, 0, 0, 0);
        }
        #pragma unroll
        for (int r = 0; r < 4; r++) {
            const int h = g*4 + r;
            if (h < HH)
                pagg[((size_t)(b*HH + h)*NN + i)*DD + 16*wv + c] = pa[r];
        }
    }
}

// ---------------------------------------------------------------------------
// K4: attn = w@v + pagg@Wsv + bsv, MFMA bf16.  FIXED R9: stage A reads 32 f32.
// ---------------------------------------------------------------------------
__global__ __launch_bounds__(256) void k_av(
    const float* __restrict__ w, const float* __restrict__ v_,
    const float* __restrict__ pagg, const float* __restrict__ Wsv,
    const float* __restrict__ bsv, float* __restrict__ attn)
{
    const int bh = blockIdx.y;
    const int b = bh / HH, h = bh % HH;
    const int i0 = blockIdx.x * 128;
    __shared__ __align__(16) unsigned Alds[128*36];
    __shared__ __align__(16) unsigned Blds[64*36];
    const int tid = threadIdx.x;
    const int wv  = tid >> 6, lane = tid & 63;
    const int fr  = lane & 15, kg = lane >> 4;

    f32x4 acc[2][4];
    #pragma unroll
    for (int i=0;i<2;i++){
        #pragma unroll
        for (int j=0;j<4;j++){ acc[i][j][0]=0.f; acc[i][j][1]=0.f; acc[i][j][2]=0.f; acc[i][j][3]=0.f; }
    }

    for (int step = 0; step < 7; step++) {
        const int j0 = step * 64;
        {   // stage A rows: w (steps 0-5) or pagg (step 6); 32 f32/thread
            const int m = tid >> 1, kh = tid & 1;
            const float4* ap = (step < 6)
                ? reinterpret_cast<const float4*>(w    + ((size_t)bh*NN + i0 + m)*NN  + j0 + kh*32)
                : reinterpret_cast<const float4*>(pagg + ((size_t)bh*NN + i0 + m)*PHH + kh*32);
            uint4 pa[4];
            pk32(ap, pa);
            #pragma unroll
            for (int e = 0; e < 4; e++)
                *reinterpret_cast<uint4*>(&Alds[m*36 + kh*16 + 4*e]) = pa[e];
        }
        {   // stage B^T: v (steps 0-5) or Wsv (step 6); column reads
            const int d = tid & 63, kq = tid >> 6;
            const float* vp = (step < 6)
                ? (v_  + ((size_t)bh*NN + j0 + kq*16)*DD + d)
                : (Wsv + (size_t)(kq*16)*DD + d);
            float x[16];
            #pragma unroll
            for (int t = 0; t < 16; t++) x[t] = vp[(size_t)t*DD];
            uint4 p0,p1;
            p0.x=pk2bf(x[0],x[1]);   p0.y=pk2bf(x[2],x[3]);
            p0.z=pk2bf(x[4],x[5]);   p0.w=pk2bf(x[6],x[7]);
            p1.x=pk2bf(x[8],x[9]);   p1.y=pk2bf(x[10],x[11]);
            p1.z=pk2bf(x[12],x[13]); p1.w=pk2bf(x[14],x[15]);
            *reinterpret_cast<uint4*>(&Blds[d*36 + kq*8    ]) = p0;
            *reinterpret_cast<uint4*>(&Blds[d*36 + kq*8 + 4]) = p1;
        }
        __syncthreads();
        #pragma unroll
        for (int ks = 0; ks < 2; ks++) {
            U8 au[2], bu[4];
            #pragma unroll
            for (int mt = 0; mt < 2; mt++)
                au[mt].u = *reinterpret_cast<const uint4*>(&Alds[(wv*32 + mt*16 + fr)*36 + ks*16 + kg*4]);
            #pragma unroll
            for (int nt = 0; nt < 4; nt++)
                bu[nt].u = *reinterpret_cast<const uint4*>(&Blds[(nt*16 + fr)*36 + ks*16 + kg*4]);
            #pragma unroll
            for (int mt = 0; mt < 2; mt++)
                #pragma unroll
                for (int nt = 0; nt < 4; nt++)
                    acc[mt][nt] = __builtin_amdgcn_mfma_f32_16x16x32_bf16(
                        au[mt].v, bu[nt].v, acc[mt][nt], 0, 0, 0);
        }
        __syncthreads();
    }
    #pragma unroll
    for (int nt = 0; nt < 4; nt++) {
        const int d = nt*16 + fr;
        const float bv_ = bsv[d];
        #pragma unroll
        for (int mt = 0; mt < 2; mt++) {
            #pragma unroll
            for (int r = 0; r < 4; r++) {
                const int i = i0 + wv*32 + mt*16 + kg*4 + r;
                attn[((size_t)b*NN + i)*HSZ + h*DD + d] = acc[mt][nt][r] + bv_;
            }
        }
    }
}

// ---------------------------------------------------------------------------
// K5a: tres = nodes + relu(attn @ Wo + bo)   -- MFMA (validated R7)
// ---------------------------------------------------------------------------
__global__ __launch_bounds__(256) void k_proj(
    const float* __restrict__ attn, const float* __restrict__ Wo,
    const float* __restrict__ bo, const float* __restrict__ nodes,
    float* __restrict__ tres)
{
    __shared__ __align__(16) unsigned Alds[128*20];
    __shared__ __align__(16) unsigned Blds[128*20];

    const int row0 = blockIdx.x * 128;
    const int col0 = blockIdx.y * 128;
    const int tid  = threadIdx.x;
    const int wv   = tid >> 6, lane = tid & 63;
    const int wm   = wv & 1,  wn   = wv >> 1;
    const int fr   = lane & 15, kg = lane >> 4;

    f32x4 acc[4][4];
    #pragma unroll
    for (int i=0;i<4;i++){
        #pragma unroll
        for (int j=0;j<4;j++){ acc[i][j][0]=0.f; acc[i][j][1]=0.f; acc[i][j][2]=0.f; acc[i][j][3]=0.f; }
    }

    for (int k0 = 0; k0 < HSZ; k0 += 32) {
        {
            const int m = tid >> 1, kh = tid & 1;
            const float4* ap = reinterpret_cast<const float4*>(attn + (size_t)(row0 + m)*HSZ + k0 + kh*16);
            float4 a0 = ap[0], a1 = ap[1], a2 = ap[2], a3 = ap[3];
            uint4 p0, p1;
            p0.x = pk2bf(a0.x,a0.y); p0.y = pk2bf(a0.z,a0.w);
            p0.z = pk2bf(a1.x,a1.y); p0.w = pk2bf(a1.z,a1.w);
            p1.x = pk2bf(a2.x,a2.y); p1.y = pk2bf(a2.z,a2.w);
            p1.z = pk2bf(a3.x,a3.y); p1.w = pk2bf(a3.z,a3.w);
            *reinterpret_cast<uint4*>(&Alds[m*20 + kh*8    ]) = p0;
            *reinterpret_cast<uint4*>(&Alds[m*20 + kh*8 + 4]) = p1;
        }
        {
            const int n = tid & 127, kq = tid >> 7;
            const float* wp = Wo + (size_t)(k0 + kq*16)*HSZ + col0 + n;
            float x[16];
            #pragma unroll
            for (int j = 0; j < 16; j++) x[j] = wp[(size_t)j*HSZ];
            uint4 p0, p1;
            p0.x = pk2bf(x[0],x[1]);   p0.y = pk2bf(x[2],x[3]);
            p0.z = pk2bf(x[4],x[5]);   p0.w = pk2bf(x[6],x[7]);
            p1.x = pk2bf(x[8],x[9]);   p1.y = pk2bf(x[10],x[11]);
            p1.z = pk2bf(x[12],x[13]); p1.w = pk2bf(x[14],x[15]);
            *reinterpret_cast<uint4*>(&Blds[n*20 + kq*8    ]) = p0;
            *reinterpret_cast<uint4*>(&Blds[n*20 + kq*8 + 4]) = p1;
        }
        __syncthreads();
        U8 au[4], bu[4];
        #pragma unroll
        for (int t = 0; t < 4; t++) {
            au[t].u = *reinterpret_cast<const uint4*>(&Alds[(wm*64 + t*16 + fr)*20 + kg*4]);
            bu[t].u = *reinterpret_cast<const uint4*>(&Blds[(wn*64 + t*16 + fr)*20 + kg*4]);
        }
        #pragma unroll
        for (int mt = 0; mt < 4; mt++)
            #pragma unroll
            for (int nt = 0; nt < 4; nt++)
                acc[mt][nt] = __builtin_amdgcn_mfma_f32_16x16x32_bf16(
                    au[mt].v, bu[nt].v, acc[mt][nt], 0, 0, 0);
        __syncthreads();
    }
    #pragma unroll
    for (int nt = 0; nt < 4; nt++) {
        const int col = col0 + wn*64 + nt*16 + fr;
        const float bov = bo[col];
        #pragma unroll
        for (int mt = 0; mt < 4; mt++) {
            #pragma unroll
            for (int r = 0; r < 4; r++) {
                const int m = row0 + wm*64 + mt*16 + kg*4 + r;
                const float val = fmaxf(acc[mt][nt][r] + bov, 0.f) + nodes[(size_t)m*HSZ + col];
                tres[(size_t)m*HSZ + col] = val;
            }
        }
    }
}

// ---------------------------------------------------------------------------
// K5b: row LayerNorm over 768 -> out0 (f32)
// ---------------------------------------------------------------------------
__global__ __launch_bounds__(256) void k_ln(
    const float* __restrict__ tres, const float* __restrict__ g,
    const float* __restrict__ bta, float* __restrict__ out0)
{
    const int row = blockIdx.x;
    const float* x = tres + (size_t)row * HSZ;
    const int tid = threadIdx.x;
    const int wid = tid >> 6, lane = tid & 63;
    __shared__ float r4[4];
    __shared__ float sc[2];
    float v0 = x[tid], v1 = x[tid+256], v2 = x[tid+512];
    float s = v0 + v1 + v2;
    #pragma unroll
    for (int o = 32; o > 0; o >>= 1) s += __shfl_xor(s, o, 64);
    if (lane == 0) r4[wid] = s;
    __syncthreads();
    if (tid == 0) sc[0] = (r4[0]+r4[1]+r4[2]+r4[3]) * (1.f/768.f);
    __syncthreads();
    const float m = sc[0];
    const float d0 = v0-m, d1 = v1-m, d2 = v2-m;
    float vs = d0*d0 + d1*d1 + d2*d2;
    #pragma unroll
    for (int o = 32; o > 0; o >>= 1) vs += __shfl_xor(vs, o, 64);
    if (lane == 0) r4[wid] = vs;
    __syncthreads();
    if (tid == 0) sc[1] = rsqrtf((r4[0]+r4[1]+r4[2]+r4[3]) * (1.f/768.f) + 1e-5f);
    __syncthreads();
    const float rs = sc[1];
    out0[(size_t)row*HSZ + tid      ] = d0*rs*g[tid      ] + bta[tid      ];
    out0[(size_t)row*HSZ + tid + 256] = d1*rs*g[tid + 256] + bta[tid + 256];
    out0[(size_t)row*HSZ + tid + 512] = d2*rs*g[tid + 512] + bta[tid + 512];
}

// ---------------------------------------------------------------------------
extern "C" void kernel_launch(void* const* d_in, const int* in_sizes, int n_in,
                              void* d_out, int out_size, void* d_ws, size_t ws_size,
                              hipStream_t stream)
{
    (void)in_sizes; (void)n_in; (void)out_size; (void)ws_size;
    const float* nodes = (const float*)d_in[0];
    const float* bias  = (const float*)d_in[1];
    const float* paths = (const float*)d_in[2];
    const float* Wq = (const float*)d_in[3];
    const float* bq = (const float*)d_in[4];
    const float* Wk = (const float*)d_in[5];
    const float* bk = (const float*)d_in[6];
    const float* Wv = (const float*)d_in[7];
    const float* bv = (const float*)d_in[8];
    const float* Wsk= (const float*)d_in[9];
    const float* Wsv= (const float*)d_in[11];
    const float* bsv= (const float*)d_in[12];
    const float* Wo = (const float*)d_in[13];
    const float* bo = (const float*)d_in[14];
    const float* lng= (const float*)d_in[15];
    const float* lnb= (const float*)d_in[16];
    const float* plg= (const float*)d_in[17];
    const float* plb= (const float*)d_in[18];

    float* ws   = (float*)d_ws;
    float* q_s  = ws;
    float* kbuf = ws + 2359296;
    float* vbuf = ws + 4718592;
    float* qsk  = ws + 7077888;
    float* wc   = ws + 9474048;
    float* attn = q_s;
    float* pagg = kbuf;
    float* tres = wc;

    float* out0 = (float*)d_out;
    float* wout = out0 + (size_t)BB*NN*HSZ;

    hipLaunchKernelGGL(k_qkv,    dim3(24,6,3), dim3(256), 0, stream,
                       nodes, Wq,bq, Wk,bk, Wv,bv, q_s, kbuf, vbuf);
    hipLaunchKernelGGL(k_qsk,    dim3(9216),   dim3(256), 0, stream,
                       q_s, Wsk, qsk);
    hipLaunchKernelGGL(k_scores, dim3(3,3,96), dim3(256), 0, stream,
                       q_s, kbuf, wc);
    hipLaunchKernelGGL(k_soft,   dim3(3072),   dim3(384), 0, stream,
                       paths, bias, plg, plb, wc, qsk, pagg, wout);
    hipLaunchKernelGGL(k_av,     dim3(3,96),   dim3(256), 0, stream,
                       wout, vbuf, pagg, Wsv, bsv, attn);
    hipLaunchKernelGGL(k_proj,   dim3(24,6),   dim3(256), 0, stream,
                       attn, Wo, bo, nodes, tres);
    hipLaunchKernelGGL(k_ln,     dim3(3072),   dim3(256), 0, stream,
                       tres, lng, lnb, out0);
}

// Round 11
// 283.630 us; speedup vs baseline: 3.0568x; 1.2188x over previous
//
#include <hip/hip_runtime.h>
#include <hip/hip_bf16.h>

typedef __hip_bfloat16 bf16;
typedef __attribute__((ext_vector_type(8))) short short8b;   // 8 bf16 (MFMA operand)
typedef __attribute__((ext_vector_type(4))) float f32x4;     // MFMA accumulator

#define BB  8
#define NN  384
#define HH  12
#define HSZ 768
#define DD  64
#define PHH 64
#define PSTR 386   // pLNT row stride in u32 words
#define SWS  194   // sw row stride in u32 words

__device__ __forceinline__ float bflo(unsigned u){ union{unsigned q; float f;} c; c.q = u << 16;        return c.f; }
__device__ __forceinline__ float bfhi(unsigned u){ union{unsigned q; float f;} c; c.q = u & 0xffff0000u; return c.f; }

// pack two f32 into a u32 of two RNE-rounded bf16 (lo, hi)
__device__ __forceinline__ unsigned pk2bf(float lo, float hi){
    union{float f; unsigned u;} a, b; a.f = lo; b.f = hi;
    unsigned ua = a.u + 0x7fffu + ((a.u >> 16) & 1u);
    unsigned ub = b.u + 0x7fffu + ((b.u >> 16) & 1u);
    return (ua >> 16) | (ub & 0xffff0000u);
}

union U8 { uint4 u; short8b v; };

// pack 8 consecutive float4 (32 f32) into 4 uint4 (16 bf16-pair words)
__device__ __forceinline__ void pk32(const float4* p, uint4* o){
    #pragma unroll
    for (int e = 0; e < 4; e++) {
        float4 x = p[2*e], y = p[2*e+1];
        o[e].x = pk2bf(x.x, x.y); o[e].y = pk2bf(x.z, x.w);
        o[e].z = pk2bf(y.x, y.y); o[e].w = pk2bf(y.z, y.w);
    }
}

// ---------------------------------------------------------------------------
// K1: QKV projection, MFMA bf16.  (validated R6/R7)
// ---------------------------------------------------------------------------
__global__ __launch_bounds__(256) void k_qkv(
    const float* __restrict__ nodes,
    const float* __restrict__ Wq, const float* __restrict__ bq,
    const float* __restrict__ Wk, const float* __restrict__ bk,
    const float* __restrict__ Wv, const float* __restrict__ bv,
    float* __restrict__ oq, float* __restrict__ okk, float* __restrict__ ov)
{
    const int which = blockIdx.z;
    const float* __restrict__ W   = which==0 ? Wq : (which==1 ? Wk : Wv);
    const float* __restrict__ bia = which==0 ? bq : (which==1 ? bk : bv);
    float* __restrict__ out       = which==0 ? oq : (which==1 ? okk : ov);
    const float scale = which==0 ? 0.125f : 1.0f;

    __shared__ __align__(16) unsigned Alds[128*20];
    __shared__ __align__(16) unsigned Blds[128*20];

    const int row0 = blockIdx.x * 128;
    const int col0 = blockIdx.y * 128;
    const int tid  = threadIdx.x;
    const int wv   = tid >> 6, lane = tid & 63;
    const int wm   = wv & 1,  wn   = wv >> 1;
    const int fr   = lane & 15, kg = lane >> 4;

    f32x4 acc[4][4];
    #pragma unroll
    for (int i=0;i<4;i++){
        #pragma unroll
        for (int j=0;j<4;j++){ acc[i][j][0]=0.f; acc[i][j][1]=0.f; acc[i][j][2]=0.f; acc[i][j][3]=0.f; }
    }

    for (int k0 = 0; k0 < HSZ; k0 += 32) {
        {   // stage A: row m, k-half kh (16 f32 -> 8 words)
            const int m = tid >> 1, kh = tid & 1;
            const float4* ap = reinterpret_cast<const float4*>(nodes + (size_t)(row0 + m)*HSZ + k0 + kh*16);
            float4 a0 = ap[0], a1 = ap[1], a2 = ap[2], a3 = ap[3];
            uint4 p0, p1;
            p0.x = pk2bf(a0.x,a0.y); p0.y = pk2bf(a0.z,a0.w);
            p0.z = pk2bf(a1.x,a1.y); p0.w = pk2bf(a1.z,a1.w);
            p1.x = pk2bf(a2.x,a2.y); p1.y = pk2bf(a2.z,a2.w);
            p1.z = pk2bf(a3.x,a3.y); p1.w = pk2bf(a3.z,a3.w);
            *reinterpret_cast<uint4*>(&Alds[m*20 + kh*8    ]) = p0;
            *reinterpret_cast<uint4*>(&Alds[m*20 + kh*8 + 4]) = p1;
        }
        {   // stage B (column reads of W)
            const int n = tid & 127, kq = tid >> 7;
            const float* wp = W + (size_t)(k0 + kq*16)*HSZ + col0 + n;
            float x[16];
            #pragma unroll
            for (int j = 0; j < 16; j++) x[j] = wp[(size_t)j*HSZ];
            uint4 p0, p1;
            p0.x = pk2bf(x[0],x[1]);   p0.y = pk2bf(x[2],x[3]);
            p0.z = pk2bf(x[4],x[5]);   p0.w = pk2bf(x[6],x[7]);
            p1.x = pk2bf(x[8],x[9]);   p1.y = pk2bf(x[10],x[11]);
            p1.z = pk2bf(x[12],x[13]); p1.w = pk2bf(x[14],x[15]);
            *reinterpret_cast<uint4*>(&Blds[n*20 + kq*8    ]) = p0;
            *reinterpret_cast<uint4*>(&Blds[n*20 + kq*8 + 4]) = p1;
        }
        __syncthreads();
        U8 au[4], bu[4];
        #pragma unroll
        for (int t = 0; t < 4; t++) {
            au[t].u = *reinterpret_cast<const uint4*>(&Alds[(wm*64 + t*16 + fr)*20 + kg*4]);
            bu[t].u = *reinterpret_cast<const uint4*>(&Blds[(wn*64 + t*16 + fr)*20 + kg*4]);
        }
        #pragma unroll
        for (int mt = 0; mt < 4; mt++)
            #pragma unroll
            for (int nt = 0; nt < 4; nt++)
                acc[mt][nt] = __builtin_amdgcn_mfma_f32_16x16x32_bf16(
                    au[mt].v, bu[nt].v, acc[mt][nt], 0, 0, 0);
        __syncthreads();
    }
    #pragma unroll
    for (int nt = 0; nt < 4; nt++) {
        const int col = col0 + wn*64 + nt*16 + fr;
        const int h = col >> 6, d = col & 63;
        const float bv_ = bia[col];
        #pragma unroll
        for (int mt = 0; mt < 4; mt++) {
            #pragma unroll
            for (int r = 0; r < 4; r++) {
                const int m = row0 + wm*64 + mt*16 + kg*4 + r;
                const int b_ = m / NN, n_ = m % NN;
                out[(((size_t)b_*HH + h)*NN + n_)*DD + d] = (acc[mt][nt][r] + bv_) * scale;
            }
        }
    }
}

// ---------------------------------------------------------------------------
// K1b: qsk = q_s @ Wsk^T, MFMA.  M=36864 rows, N=64 (ph), K=64 (d).
// Grid 288 x 256.  A rows [m][k] stride 36; B = Wsk rows [ph][d] stride 36.
// ---------------------------------------------------------------------------
__global__ __launch_bounds__(256) void k_qsk(
    const float* __restrict__ q_s, const float* __restrict__ Wsk,
    float* __restrict__ qsk)
{
    __shared__ __align__(16) unsigned Alds[128*36];
    __shared__ __align__(16) unsigned Blds[64*36];
    const int row0 = blockIdx.x * 128;
    const int tid = threadIdx.x;
    const int wv = tid >> 6, lane = tid & 63;
    const int fr = lane & 15, kg = lane >> 4;

    {   // stage A: row m = tid>>1, half kh = tid&1 (32 f32 -> 16 words)
        const int m = tid >> 1, kh = tid & 1;
        const float4* ap = reinterpret_cast<const float4*>(q_s + (size_t)(row0 + m)*DD + kh*32);
        uint4 pa[4]; pk32(ap, pa);
        #pragma unroll
        for (int e = 0; e < 4; e++)
            *reinterpret_cast<uint4*>(&Alds[m*36 + kh*16 + 4*e]) = pa[e];
    }
    {   // stage B: Wsk row n = tid&63, quarter kq = tid>>6 (16 f32 -> 8 words)
        const int n = tid & 63, kq = tid >> 6;
        const float4* bp = reinterpret_cast<const float4*>(Wsk + (size_t)n*DD + kq*16);
        float4 b0 = bp[0], b1 = bp[1], b2 = bp[2], b3 = bp[3];
        uint4 p0, p1;
        p0.x = pk2bf(b0.x,b0.y); p0.y = pk2bf(b0.z,b0.w);
        p0.z = pk2bf(b1.x,b1.y); p0.w = pk2bf(b1.z,b1.w);
        p1.x = pk2bf(b2.x,b2.y); p1.y = pk2bf(b2.z,b2.w);
        p1.z = pk2bf(b3.x,b3.y); p1.w = pk2bf(b3.z,b3.w);
        *reinterpret_cast<uint4*>(&Blds[n*36 + kq*8    ]) = p0;
        *reinterpret_cast<uint4*>(&Blds[n*36 + kq*8 + 4]) = p1;
    }
    __syncthreads();

    f32x4 acc[2][4];
    #pragma unroll
    for (int i=0;i<2;i++){
        #pragma unroll
        for (int j=0;j<4;j++){ acc[i][j][0]=0.f; acc[i][j][1]=0.f; acc[i][j][2]=0.f; acc[i][j][3]=0.f; }
    }
    #pragma unroll
    for (int ks = 0; ks < 2; ks++) {
        U8 au[2], bu[4];
        #pragma unroll
        for (int mt = 0; mt < 2; mt++)
            au[mt].u = *reinterpret_cast<const uint4*>(&Alds[(wv*32 + mt*16 + fr)*36 + ks*16 + kg*4]);
        #pragma unroll
        for (int nt = 0; nt < 4; nt++)
            bu[nt].u = *reinterpret_cast<const uint4*>(&Blds[(nt*16 + fr)*36 + ks*16 + kg*4]);
        #pragma unroll
        for (int mt = 0; mt < 2; mt++)
            #pragma unroll
            for (int nt = 0; nt < 4; nt++)
                acc[mt][nt] = __builtin_amdgcn_mfma_f32_16x16x32_bf16(
                    au[mt].v, bu[nt].v, acc[mt][nt], 0, 0, 0);
    }
    #pragma unroll
    for (int nt = 0; nt < 4; nt++) {
        #pragma unroll
        for (int mt = 0; mt < 2; mt++) {
            #pragma unroll
            for (int r = 0; r < 4; r++) {
                const int m = row0 + wv*32 + mt*16 + kg*4 + r;
                qsk[(size_t)m*DD + nt*16 + fr] = acc[mt][nt][r];
            }
        }
    }
}

// ---------------------------------------------------------------------------
// K2: content scores, MFMA bf16.  (validated R9)
// ---------------------------------------------------------------------------
__global__ __launch_bounds__(256) void k_scores(
    const float* __restrict__ q_s, const float* __restrict__ kk_, float* __restrict__ wc)
{
    const int bh = blockIdx.z;
    __shared__ __align__(16) unsigned Alds[128*36];
    __shared__ __align__(16) unsigned Blds[128*36];
    const int i0 = blockIdx.x * 128, j0 = blockIdx.y * 128;
    const int tid = threadIdx.x;
    const int wv  = tid >> 6, lane = tid & 63;
    const int wm  = wv & 1,  wn   = wv >> 1;
    const int fr  = lane & 15, kg = lane >> 4;

    {   // stage: row m = tid>>1, half kh = tid&1 -> 32 f32 = 16 words each
        const int m = tid >> 1, kh = tid & 1;
        const float4* ap = reinterpret_cast<const float4*>(q_s + ((size_t)bh*NN + i0 + m)*DD + kh*32);
        const float4* bp = reinterpret_cast<const float4*>(kk_ + ((size_t)bh*NN + j0 + m)*DD + kh*32);
        uint4 pa[4], pbq[4];
        pk32(ap, pa);
        pk32(bp, pbq);
        #pragma unroll
        for (int e = 0; e < 4; e++) {
            *reinterpret_cast<uint4*>(&Alds[m*36 + kh*16 + 4*e]) = pa[e];
            *reinterpret_cast<uint4*>(&Blds[m*36 + kh*16 + 4*e]) = pbq[e];
        }
    }
    __syncthreads();

    f32x4 acc[4][4];
    #pragma unroll
    for (int i=0;i<4;i++){
        #pragma unroll
        for (int j=0;j<4;j++){ acc[i][j][0]=0.f; acc[i][j][1]=0.f; acc[i][j][2]=0.f; acc[i][j][3]=0.f; }
    }
    #pragma unroll
    for (int ks = 0; ks < 2; ks++) {
        U8 au[4], bu[4];
        #pragma unroll
        for (int t = 0; t < 4; t++) {
            au[t].u = *reinterpret_cast<const uint4*>(&Alds[(wm*64 + t*16 + fr)*36 + ks*16 + kg*4]);
            bu[t].u = *reinterpret_cast<const uint4*>(&Blds[(wn*64 + t*16 + fr)*36 + ks*16 + kg*4]);
        }
        #pragma unroll
        for (int mt = 0; mt < 4; mt++)
            #pragma unroll
            for (int nt = 0; nt < 4; nt++)
                acc[mt][nt] = __builtin_amdgcn_mfma_f32_16x16x32_bf16(
                    au[mt].v, bu[nt].v, acc[mt][nt], 0, 0, 0);
    }
    #pragma unroll
    for (int nt = 0; nt < 4; nt++) {
        const int j = j0 + wn*64 + nt*16 + fr;
        #pragma unroll
        for (int mt = 0; mt < 4; mt++) {
            #pragma unroll
            for (int r = 0; r < 4; r++) {
                const int i = i0 + wm*64 + mt*16 + kg*4 + r;
                wc[((size_t)bh*NN + i)*NN + j] = acc[mt][nt][r];
            }
        }
    }
}

// ---------------------------------------------------------------------------
// K3: fused per-(b,i), MFMA scores + pagg.  R10: paths loads issued FIRST
// (before any LDS fill / barrier) so HBM latency hides under setup.
// ---------------------------------------------------------------------------
__global__ __launch_bounds__(384) void k_soft(
    const float* __restrict__ paths, const float* __restrict__ bias,
    const float* __restrict__ pg, const float* __restrict__ pb,
    const float* __restrict__ wc, const float* __restrict__ qsk,
    float* __restrict__ pagg, float* __restrict__ w_out)
{
    const int bi = blockIdx.x;
    const int b = bi / NN, i = bi % NN;
    __shared__ __align__(16) unsigned pLNT[32 * PSTR];
    __shared__ __align__(16) unsigned sw32[16 * SWS];
    __shared__ __align__(16) unsigned qskA[16 * 36];
    __shared__ float redM[6][16];
    __shared__ float redS[6][16];
    __shared__ float pgf[64], pbf[64];
    const int tid  = threadIdx.x;
    const int wv   = tid >> 6, lane = tid & 63;
    const int g    = lane >> 4, c = lane & 15;
    const int jbase = wv*64 + c;

    // (1) paths row j = tid into registers -- issued first, no barrier above
    float x[64];
    {
        const float4* src = reinterpret_cast<const float4*>(paths + ((size_t)bi * NN + tid) * PHH);
        #pragma unroll
        for (int t = 0; t < 16; t++) {
            float4 u = src[t];
            x[4*t]=u.x; x[4*t+1]=u.y; x[4*t+2]=u.z; x[4*t+3]=u.w;
        }
    }
    // (2) hoisted phase-2 operands
    float wcv[4][4], biasj[4];
    #pragma unroll
    for (int nt = 0; nt < 4; nt++) {
        const int j = jbase + nt*16;
        biasj[nt] = bias[b*NN + j];
        #pragma unroll
        for (int r = 0; r < 4; r++) {
            const int h = g*4 + r;
            wcv[nt][r] = (h < HH) ? wc[((size_t)(b*HH + h)*NN + i)*NN + j] : 0.f;
        }
    }
    // (3) small LDS fills
    if (tid < 64) { pgf[tid] = pg[tid]; pbf[tid] = pb[tid]; }
    {   // fill qskA: h = tid>>5 (0..11), 2 ph per thread; zero rows 12..15
        const int h = tid >> 5, t2 = tid & 31;
        const size_t r0 = ((size_t)(b*HH + h)*NN + i)*DD;
        const float q0 = qsk[r0 + 2*t2], q1 = qsk[r0 + 2*t2 + 1];
        qskA[h*36 + t2] = pk2bf(q0, q1);
        if (tid < 144) qskA[432 + tid] = 0u;
    }
    __syncthreads();

    {   // (4) LayerNorm from registers -> pLNT transposed packed
        float m0 = 0.f, m1 = 0.f;
        #pragma unroll
        for (int t = 0; t < 32; t++){ m0 += x[2*t]; m1 += x[2*t+1]; }
        const float m = (m0+m1)*(1.f/64.f);
        float v0 = 0.f, v1 = 0.f;
        #pragma unroll
        for (int t = 0; t < 32; t++){
            float a = x[2*t]-m, d = x[2*t+1]-m;
            v0 = fmaf(a,a,v0); v1 = fmaf(d,d,v1);
        }
        const float rs = rsqrtf((v0+v1)*(1.f/64.f) + 1e-5f);
        #pragma unroll
        for (int w = 0; w < 32; w++){
            const float lo = (x[2*w  ]-m)*rs*pgf[2*w  ] + pbf[2*w  ];
            const float hi = (x[2*w+1]-m)*rs*pgf[2*w+1] + pbf[2*w+1];
            pLNT[w*PSTR + tid] = pk2bf(lo, hi);
        }
    }
    __syncthreads();

    // ---- phase 2: scoresT via MFMA.  D[h = 4g+r][j = 64wv + 16nt + c]
    f32x4 sc[4];
    #pragma unroll
    for (int nt=0;nt<4;nt++){ sc[nt][0]=0.f; sc[nt][1]=0.f; sc[nt][2]=0.f; sc[nt][3]=0.f; }
    #pragma unroll
    for (int kh = 0; kh < 2; kh++) {
        U8 a; a.u = *reinterpret_cast<const uint4*>(&qskA[c*36 + kh*16 + g*4]);
        #pragma unroll
        for (int nt = 0; nt < 4; nt++) {
            const unsigned* pb_ = &pLNT[(kh*16 + g*4)*PSTR + jbase + nt*16];
            uint4 bw;
            bw.x = pb_[0]; bw.y = pb_[PSTR]; bw.z = pb_[2*PSTR]; bw.w = pb_[3*PSTR];
            U8 bb; bb.u = bw;
            sc[nt] = __builtin_amdgcn_mfma_f32_16x16x32_bf16(a.v, bb.v, sc[nt], 0, 0, 0);
        }
    }
    #pragma unroll
    for (int nt = 0; nt < 4; nt++)
        #pragma unroll
        for (int r = 0; r < 4; r++)
            sc[nt][r] += wcv[nt][r] + biasj[nt];

    // softmax: per-head reduce over j (16-lane group + cross-wave LDS)
    float e_[4][4], inv_[4];
    {
        float mr[4];
        #pragma unroll
        for (int r = 0; r < 4; r++) {
            float m2 = fmaxf(fmaxf(sc[0][r], sc[1][r]), fmaxf(sc[2][r], sc[3][r]));
            #pragma unroll
            for (int o = 1; o <= 8; o <<= 1) m2 = fmaxf(m2, __shfl_xor(m2, o, 64));
            mr[r] = m2;
        }
        if (c == 0) {
            #pragma unroll
            for (int r = 0; r < 4; r++) redM[wv][g*4 + r] = mr[r];
        }
        __syncthreads();
        #pragma unroll
        for (int r = 0; r < 4; r++) {
            float Mv = redM[0][g*4 + r];
            #pragma unroll
            for (int w2 = 1; w2 < 6; w2++) Mv = fmaxf(Mv, redM[w2][g*4 + r]);
            float s2 = 0.f;
            #pragma unroll
            for (int nt = 0; nt < 4; nt++){ e_[nt][r] = __expf(sc[nt][r] - Mv); s2 += e_[nt][r]; }
            #pragma unroll
            for (int o = 1; o <= 8; o <<= 1) s2 += __shfl_xor(s2, o, 64);
            mr[r] = s2;
        }
        if (c == 0) {
            #pragma unroll
            for (int r = 0; r < 4; r++) redS[wv][g*4 + r] = mr[r];
        }
        __syncthreads();
        #pragma unroll
        for (int r = 0; r < 4; r++) {
            float Sv = redS[0][g*4 + r];
            #pragma unroll
            for (int w2 = 1; w2 < 6; w2++) Sv += redS[w2][g*4 + r];
            inv_[r] = 1.f / Sv;
        }
    }
    // w: store to global (h<12) + pack into sw (A-operand layout for pagg)
    #pragma unroll
    for (int nt = 0; nt < 4; nt++) {
        const int j = jbase + nt*16;
        #pragma unroll
        for (int r = 0; r < 4; r++) {
            const int h = g*4 + r;
            const float wgt = e_[nt][r] * inv_[r];
            if (h < HH) w_out[((size_t)(b*HH + h)*NN + i)*NN + j] = wgt;
            const float oth = __shfl_xor(wgt, 1, 64);
            if ((c & 1) == 0) sw32[h*SWS + (j >> 1)] = pk2bf(wgt, oth);
        }
    }
    __syncthreads();

    // ---- phase 3: pagg via MFMA.  waves 0..3: ph-tile = 16*wv.
    if (wv < 4) {
        f32x4 pa; pa[0]=0.f; pa[1]=0.f; pa[2]=0.f; pa[3]=0.f;
        const int prow = 8*wv + (c >> 1);
        const bool hi = (c & 1);
        #pragma unroll 4
        for (int kt = 0; kt < 12; kt++) {
            uint2 a0 = *reinterpret_cast<const uint2*>(&sw32[c*SWS + kt*16 + g*4]);
            uint2 a1 = *reinterpret_cast<const uint2*>(&sw32[c*SWS + kt*16 + g*4 + 2]);
            U8 af; af.u.x = a0.x; af.u.y = a0.y; af.u.z = a1.x; af.u.w = a1.y;
            const unsigned* pr = &pLNT[prow*PSTR + 32*kt + 8*g];
            uint2 w01 = *reinterpret_cast<const uint2*>(&pr[0]);
            uint2 w23 = *reinterpret_cast<const uint2*>(&pr[2]);
            uint2 w45 = *reinterpret_cast<const uint2*>(&pr[4]);
            uint2 w67 = *reinterpret_cast<const uint2*>(&pr[6]);
            uint4 bw;
            if (hi) {
                bw.x = (w01.x >> 16) | (w01.y & 0xffff0000u);
                bw.y = (w23.x >> 16) | (w23.y & 0xffff0000u);
                bw.z = (w45.x >> 16) | (w45.y & 0xffff0000u);
                bw.w = (w67.x >> 16) | (w67.y & 0xffff0000u);
            } else {
                bw.x = (w01.x & 0xffffu) | (w01.y << 16);
                bw.y = (w23.x & 0xffffu) | (w23.y << 16);
                bw.z = (w45.x & 0xffffu) | (w45.y << 16);
                bw.w = (w67.x & 0xffffu) | (w67.y << 16);
            }
            U8 bf_; bf_.u = bw;
            pa = __builtin_amdgcn_mfma_f32_16x16x32_bf16(af.v, bf_.v, pa, 0, 0, 0);
        }
        #pragma unroll
        for (int r = 0; r < 4; r++) {
            const int h = g*4 + r;
            if (h < HH)
                pagg[((size_t)(b*HH + h)*NN + i)*DD + 16*wv + c] = pa[r];
        }
    }
}

// ---------------------------------------------------------------------------
// K4: attn = w@v + pagg@Wsv + bsv, MFMA bf16.  (validated R9)
// ---------------------------------------------------------------------------
__global__ __launch_bounds__(256) void k_av(
    const float* __restrict__ w, const float* __restrict__ v_,
    const float* __restrict__ pagg, const float* __restrict__ Wsv,
    const float* __restrict__ bsv, float* __restrict__ attn)
{
    const int bh = blockIdx.y;
    const int b = bh / HH, h = bh % HH;
    const int i0 = blockIdx.x * 128;
    __shared__ __align__(16) unsigned Alds[128*36];
    __shared__ __align__(16) unsigned Blds[64*36];
    const int tid = threadIdx.x;
    const int wv  = tid >> 6, lane = tid & 63;
    const int fr  = lane & 15, kg = lane >> 4;

    f32x4 acc[2][4];
    #pragma unroll
    for (int i=0;i<2;i++){
        #pragma unroll
        for (int j=0;j<4;j++){ acc[i][j][0]=0.f; acc[i][j][1]=0.f; acc[i][j][2]=0.f; acc[i][j][3]=0.f; }
    }

    for (int step = 0; step < 7; step++) {
        const int j0 = step * 64;
        {   // stage A rows: w (steps 0-5) or pagg (step 6); 32 f32/thread
            const int m = tid >> 1, kh = tid & 1;
            const float4* ap = (step < 6)
                ? reinterpret_cast<const float4*>(w    + ((size_t)bh*NN + i0 + m)*NN  + j0 + kh*32)
                : reinterpret_cast<const float4*>(pagg + ((size_t)bh*NN + i0 + m)*PHH + kh*32);
            uint4 pa[4];
            pk32(ap, pa);
            #pragma unroll
            for (int e = 0; e < 4; e++)
                *reinterpret_cast<uint4*>(&Alds[m*36 + kh*16 + 4*e]) = pa[e];
        }
        {   // stage B^T: v (steps 0-5) or Wsv (step 6); column reads
            const int d = tid & 63, kq = tid >> 6;
            const float* vp = (step < 6)
                ? (v_  + ((size_t)bh*NN + j0 + kq*16)*DD + d)
                : (Wsv + (size_t)(kq*16)*DD + d);
            float x[16];
            #pragma unroll
            for (int t = 0; t < 16; t++) x[t] = vp[(size_t)t*DD];
            uint4 p0,p1;
            p0.x=pk2bf(x[0],x[1]);   p0.y=pk2bf(x[2],x[3]);
            p0.z=pk2bf(x[4],x[5]);   p0.w=pk2bf(x[6],x[7]);
            p1.x=pk2bf(x[8],x[9]);   p1.y=pk2bf(x[10],x[11]);
            p1.z=pk2bf(x[12],x[13]); p1.w=pk2bf(x[14],x[15]);
            *reinterpret_cast<uint4*>(&Blds[d*36 + kq*8    ]) = p0;
            *reinterpret_cast<uint4*>(&Blds[d*36 + kq*8 + 4]) = p1;
        }
        __syncthreads();
        #pragma unroll
        for (int ks = 0; ks < 2; ks++) {
            U8 au[2], bu[4];
            #pragma unroll
            for (int mt = 0; mt < 2; mt++)
                au[mt].u = *reinterpret_cast<const uint4*>(&Alds[(wv*32 + mt*16 + fr)*36 + ks*16 + kg*4]);
            #pragma unroll
            for (int nt = 0; nt < 4; nt++)
                bu[nt].u = *reinterpret_cast<const uint4*>(&Blds[(nt*16 + fr)*36 + ks*16 + kg*4]);
            #pragma unroll
            for (int mt = 0; mt < 2; mt++)
                #pragma unroll
                for (int nt = 0; nt < 4; nt++)
                    acc[mt][nt] = __builtin_amdgcn_mfma_f32_16x16x32_bf16(
                        au[mt].v, bu[nt].v, acc[mt][nt], 0, 0, 0);
        }
        __syncthreads();
    }
    #pragma unroll
    for (int nt = 0; nt < 4; nt++) {
        const int d = nt*16 + fr;
        const float bv_ = bsv[d];
        #pragma unroll
        for (int mt = 0; mt < 2; mt++) {
            #pragma unroll
            for (int r = 0; r < 4; r++) {
                const int i = i0 + wv*32 + mt*16 + kg*4 + r;
                attn[((size_t)b*NN + i)*HSZ + h*DD + d] = acc[mt][nt][r] + bv_;
            }
        }
    }
}

// ---------------------------------------------------------------------------
// K5a: tres = nodes + relu(attn @ Wo + bo)   -- MFMA (validated R7)
// ---------------------------------------------------------------------------
__global__ __launch_bounds__(256) void k_proj(
    const float* __restrict__ attn, const float* __restrict__ Wo,
    const float* __restrict__ bo, const float* __restrict__ nodes,
    float* __restrict__ tres)
{
    __shared__ __align__(16) unsigned Alds[128*20];
    __shared__ __align__(16) unsigned Blds[128*20];

    const int row0 = blockIdx.x * 128;
    const int col0 = blockIdx.y * 128;
    const int tid  = threadIdx.x;
    const int wv   = tid >> 6, lane = tid & 63;
    const int wm   = wv & 1,  wn   = wv >> 1;
    const int fr   = lane & 15, kg = lane >> 4;

    f32x4 acc[4][4];
    #pragma unroll
    for (int i=0;i<4;i++){
        #pragma unroll
        for (int j=0;j<4;j++){ acc[i][j][0]=0.f; acc[i][j][1]=0.f; acc[i][j][2]=0.f; acc[i][j][3]=0.f; }
    }

    for (int k0 = 0; k0 < HSZ; k0 += 32) {
        {
            const int m = tid >> 1, kh = tid & 1;
            const float4* ap = reinterpret_cast<const float4*>(attn + (size_t)(row0 + m)*HSZ + k0 + kh*16);
            float4 a0 = ap[0], a1 = ap[1], a2 = ap[2], a3 = ap[3];
            uint4 p0, p1;
            p0.x = pk2bf(a0.x,a0.y); p0.y = pk2bf(a0.z,a0.w);
            p0.z = pk2bf(a1.x,a1.y); p0.w = pk2bf(a1.z,a1.w);
            p1.x = pk2bf(a2.x,a2.y); p1.y = pk2bf(a2.z,a2.w);
            p1.z = pk2bf(a3.x,a3.y); p1.w = pk2bf(a3.z,a3.w);
            *reinterpret_cast<uint4*>(&Alds[m*20 + kh*8    ]) = p0;
            *reinterpret_cast<uint4*>(&Alds[m*20 + kh*8 + 4]) = p1;
        }
        {
            const int n = tid & 127, kq = tid >> 7;
            const float* wp = Wo + (size_t)(k0 + kq*16)*HSZ + col0 + n;
            float x[16];
            #pragma unroll
            for (int j = 0; j < 16; j++) x[j] = wp[(size_t)j*HSZ];
            uint4 p0, p1;
            p0.x = pk2bf(x[0],x[1]);   p0.y = pk2bf(x[2],x[3]);
            p0.z = pk2bf(x[4],x[5]);   p0.w = pk2bf(x[6],x[7]);
            p1.x = pk2bf(x[8],x[9]);   p1.y = pk2bf(x[10],x[11]);
            p1.z = pk2bf(x[12],x[13]); p1.w = pk2bf(x[14],x[15]);
            *reinterpret_cast<uint4*>(&Blds[n*20 + kq*8    ]) = p0;
            *reinterpret_cast<uint4*>(&Blds[n*20 + kq*8 + 4]) = p1;
        }
        __syncthreads();
        U8 au[4], bu[4];
        #pragma unroll
        for (int t = 0; t < 4; t++) {
            au[t].u = *reinterpret_cast<const uint4*>(&Alds[(wm*64 + t*16 + fr)*20 + kg*4]);
            bu[t].u = *reinterpret_cast<const uint4*>(&Blds[(wn*64 + t*16 + fr)*20 + kg*4]);
        }
        #pragma unroll
        for (int mt = 0; mt < 4; mt++)
            #pragma unroll
            for (int nt = 0; nt < 4; nt++)
                acc[mt][nt] = __builtin_amdgcn_mfma_f32_16x16x32_bf16(
                    au[mt].v, bu[nt].v, acc[mt][nt], 0, 0, 0);
        __syncthreads();
    }
    #pragma unroll
    for (int nt = 0; nt < 4; nt++) {
        const int col = col0 + wn*64 + nt*16 + fr;
        const float bov = bo[col];
        #pragma unroll
        for (int mt = 0; mt < 4; mt++) {
            #pragma unroll
            for (int r = 0; r < 4; r++) {
                const int m = row0 + wm*64 + mt*16 + kg*4 + r;
                const float val = fmaxf(acc[mt][nt][r] + bov, 0.f) + nodes[(size_t)m*HSZ + col];
                tres[(size_t)m*HSZ + col] = val;
            }
        }
    }
}

// ---------------------------------------------------------------------------
// K5b: row LayerNorm, 1 wave per row, 4 rows/block, no barriers/LDS.
// ---------------------------------------------------------------------------
__global__ __launch_bounds__(256) void k_ln(
    const float* __restrict__ tres, const float* __restrict__ g,
    const float* __restrict__ bta, float* __restrict__ out0)
{
    const int row  = blockIdx.x * 4 + (threadIdx.x >> 6);
    const int lane = threadIdx.x & 63;
    const float4* x4 = reinterpret_cast<const float4*>(tres + (size_t)row * HSZ);
    float4 v[3];
    #pragma unroll
    for (int t = 0; t < 3; t++) v[t] = x4[lane + t*64];
    float s = 0.f;
    #pragma unroll
    for (int t = 0; t < 3; t++) s += v[t].x + v[t].y + v[t].z + v[t].w;
    #pragma unroll
    for (int o = 32; o > 0; o >>= 1) s += __shfl_xor(s, o, 64);
    const float m = s * (1.f/768.f);
    float vs = 0.f;
    #pragma unroll
    for (int t = 0; t < 3; t++) {
        float a = v[t].x-m, b = v[t].y-m, c = v[t].z-m, d = v[t].w-m;
        vs += a*a + b*b + c*c + d*d;
    }
    #pragma unroll
    for (int o = 32; o > 0; o >>= 1) vs += __shfl_xor(vs, o, 64);
    const float rs = rsqrtf(vs * (1.f/768.f) + 1e-5f);
    const float4* g4 = reinterpret_cast<const float4*>(g);
    const float4* b4 = reinterpret_cast<const float4*>(bta);
    float4* o4 = reinterpret_cast<float4*>(out0 + (size_t)row * HSZ);
    #pragma unroll
    for (int t = 0; t < 3; t++) {
        const int idx = lane + t*64;
        float4 gg = g4[idx], bb = b4[idx], o;
        o.x = (v[t].x-m)*rs*gg.x + bb.x;
        o.y = (v[t].y-m)*rs*gg.y + bb.y;
        o.z = (v[t].z-m)*rs*gg.z + bb.z;
        o.w = (v[t].w-m)*rs*gg.w + bb.w;
        o4[idx] = o;
    }
}

// ---------------------------------------------------------------------------
extern "C" void kernel_launch(void* const* d_in, const int* in_sizes, int n_in,
                              void* d_out, int out_size, void* d_ws, size_t ws_size,
                              hipStream_t stream)
{
    (void)in_sizes; (void)n_in; (void)out_size; (void)ws_size;
    const float* nodes = (const float*)d_in[0];
    const float* bias  = (const float*)d_in[1];
    const float* paths = (const float*)d_in[2];
    const float* Wq = (const float*)d_in[3];
    const float* bq = (const float*)d_in[4];
    const float* Wk = (const float*)d_in[5];
    const float* bk = (const float*)d_in[6];
    const float* Wv = (const float*)d_in[7];
    const float* bv = (const float*)d_in[8];
    const float* Wsk= (const float*)d_in[9];
    const float* Wsv= (const float*)d_in[11];
    const float* bsv= (const float*)d_in[12];
    const float* Wo = (const float*)d_in[13];
    const float* bo = (const float*)d_in[14];
    const float* lng= (const float*)d_in[15];
    const float* lnb= (const float*)d_in[16];
    const float* plg= (const float*)d_in[17];
    const float* plb= (const float*)d_in[18];

    float* ws   = (float*)d_ws;
    float* q_s  = ws;
    float* kbuf = ws + 2359296;
    float* vbuf = ws + 4718592;
    float* qsk  = ws + 7077888;
    float* wc   = ws + 9474048;
    float* attn = q_s;
    float* pagg = kbuf;
    float* tres = wc;

    float* out0 = (float*)d_out;
    float* wout = out0 + (size_t)BB*NN*HSZ;

    hipLaunchKernelGGL(k_qkv,    dim3(24,6,3), dim3(256), 0, stream,
                       nodes, Wq,bq, Wk,bk, Wv,bv, q_s, kbuf, vbuf);
    hipLaunchKernelGGL(k_qsk,    dim3(288),    dim3(256), 0, stream,
                       q_s, Wsk, qsk);
    hipLaunchKernelGGL(k_scores, dim3(3,3,96), dim3(256), 0, stream,
                       q_s, kbuf, wc);
    hipLaunchKernelGGL(k_soft,   dim3(3072),   dim3(384), 0, stream,
                       paths, bias, plg, plb, wc, qsk, pagg, wout);
    hipLaunchKernelGGL(k_av,     dim3(3,96),   dim3(256), 0, stream,
                       wout, vbuf, pagg, Wsv, bsv, attn);
    hipLaunchKernelGGL(k_proj,   dim3(24,6),   dim3(256), 0, stream,
                       attn, Wo, bo, nodes, tres);
    hipLaunchKernelGGL(k_ln,     dim3(768),    dim3(256), 0, stream,
                       tres, lng, lnb, out0);
}